// Round 12
// baseline (337.391 us; speedup 1.0000x reference)
//
#include <hip/hip_runtime.h>
#include <math.h>

typedef _Float16 f16;
typedef _Float16 f16x4 __attribute__((ext_vector_type(4)));
typedef _Float16 f16x8 __attribute__((ext_vector_type(8)));
typedef float f32x4 __attribute__((ext_vector_type(4)));

#define SEQ   2048
#define DIM   1024
#define NH    16
#define DH    64
#define NCOLS 6144
#define NHSD  (NH*SEQ*DH)   /* 2,097,152 elements per qkv sub-tensor */
#define NTILE 136           /* lk tiles per head (triangular) */
#define MAXS  9
#define SLOTS_PER_HEAD 64   /* sum over I of NS2[I>>1] */

// pair-splits: pair a = (I0=2a, I1=2a+1); NS2 K-splits per pair.
__device__ __forceinline__ int ns2(int a) {
  const int NS2[8] = {1,1,2,3,4,5,7,9};
  return NS2[a];
}
__device__ __forceinline__ int slot_base(int I) {  // prefix of NS2[I'>>1] over I' < I
  const int PF[16] = {0,1,2,3,4,6,8,11,14,18,22,27,32,39,46,55};
  return PF[I];
}

// ---------------- R26 fused prep: prepA (256 blocks) | prepB (768) | tcast (256) ----------------
// prepB rewritten with LDS-transpose staging: the old per-j gather read 4x64B segments per wave
// (~25% coalescing) over 25MB of Wq; now the 64x128 f32 tile loads fully coalesced (512B rows)
// and frags are emitted from LDS (stride 130 f16 breaks the transposed-read bank collisions).
__global__ __launch_bounds__(256) void k_prep(const float* __restrict__ x,  f16* __restrict__ xhT,
                                              const float* __restrict__ Wq, f16* __restrict__ WqTf,
                                              const float* __restrict__ Wo, f16* __restrict__ WoT) {
  __shared__ f16 sw[64 * 130];
  int b = blockIdx.x;
  int tid = threadIdx.x;
  if (b < 256) {
    // ---- prepA: x (f32) -> A-frag-chunk tiles (already coalesced) ----
    int kt = b & 15, by = b >> 4;
    f16* dst = xhT + ((size_t)(by * 16 + kt) << 13);
#pragma unroll
    for (int i = 0; i < 4; ++i) {
      int idx = i * 256 + tid;
      int chunk = idx >> 6, lane = idx & 63;
      int rb = chunk & 7, ks = chunk >> 3;
      int row = by * 128 + rb * 16 + (lane & 15);
      int kk = kt * 64 + ks * 32 + ((lane >> 4) << 3);
      const float* p = x + (size_t)row * DIM + kk;
      float4 lo = *(const float4*)p, hi = *(const float4*)(p + 4);
      f16x8 h;
      h[0] = (f16)lo.x; h[1] = (f16)lo.y; h[2] = (f16)lo.z; h[3] = (f16)lo.w;
      h[4] = (f16)hi.x; h[5] = (f16)hi.y; h[6] = (f16)hi.z; h[7] = (f16)hi.w;
      *(f16x8*)(dst + (size_t)idx * 8) = h;
    }
  } else if (b < 1024) {
    // ---- prepB: Wq[k][n] -> B-frag-chunk tiles via LDS transpose ----
    int t = b - 256;
    int kt = t & 15, bx = t >> 4;
    // stage Wq[kt*64..+64)[bx*128..+128) coalesced, cast f16 into sw[64][130]
#pragma unroll
    for (int it = 0; it < 8; ++it) {
      int idx = it * 256 + tid;          // 0..2047
      int r = idx >> 5, c4 = idx & 31;   // row, float4-chunk
      float4 v = *(const float4*)(Wq + (size_t)(kt * 64 + r) * NCOLS + bx * 128 + c4 * 4);
      f16* d = sw + r * 130 + c4 * 4;
      d[0] = (f16)v.x; d[1] = (f16)v.y; d[2] = (f16)v.z; d[3] = (f16)v.w;
    }
    __syncthreads();
    f16* dst = WqTf + ((size_t)(bx * 16 + kt) << 13);
#pragma unroll
    for (int i = 0; i < 4; ++i) {
      int idx = i * 256 + tid;
      int chunk = idx >> 6, lane = idx & 63;
      int rb = chunk & 7, ks = chunk >> 3;
      int nl = rb * 16 + (lane & 15);
      int kl = ks * 32 + ((lane >> 4) << 3);
      f16x8 h;
#pragma unroll
      for (int j = 0; j < 8; ++j) h[j] = sw[(kl + j) * 130 + nl];
      *(f16x8*)(dst + (size_t)idx * 8) = h;
    }
  } else {
    // ---- tcast: WoT[c][r] = (f16) Wo[r][c] ----
    int t = b - 1024;
    int bc = t & 15, br = t >> 4;
    for (int it = 0; it < 16; ++it) {
      int idx = it * 256 + tid;
      int r = idx >> 6, c = idx & 63;
      sw[r * 66 + c] = (f16)Wo[(size_t)(br * 64 + r) * DIM + bc * 64 + c];
    }
    __syncthreads();
    for (int it = 0; it < 16; ++it) {
      int idx = it * 256 + tid;
      int oc = idx >> 6, orr = idx & 63;
      WoT[(size_t)(bc * 64 + oc) * DIM + br * 64 + orr] = sw[orr * 66 + oc];
    }
  }
}

// ---------------- qkv GEMM. kc(t=4), vt(t=5) in B-frag chunk tiles; t=2 written BOTH
// row-major (for k_t1lk) and transposed B-frag tiles vuF (for k_prefix). ----
__global__ __launch_bounds__(256) void k_gemm_qkv(const f16* __restrict__ xhT, const f16* __restrict__ WqTf,
                                                  f16* __restrict__ q6, f16* __restrict__ vuF) {
  __shared__ f16 sa[8192];
  __shared__ f16 sb[8192];
  int bx = blockIdx.x, by = blockIdx.y;
  int tid = threadIdx.x, w = tid >> 6, l = tid & 63, q = l >> 4, c = l & 15;
  f32x4 acc[2][8];
  const f32x4 zf = {0.f, 0.f, 0.f, 0.f};
  for (int i = 0; i < 2; ++i) for (int j = 0; j < 8; ++j) acc[i][j] = zf;

  for (int kt = 0; kt < 16; ++kt) {
    const f16* ta = xhT + ((size_t)(by * 16 + kt) << 13);
    const f16* tb = WqTf + ((size_t)(bx * 16 + kt) << 13);
    __syncthreads();
#pragma unroll
    for (int i = 0; i < 4; ++i) {
      int e = (i * 256 + tid) * 8;
      __builtin_amdgcn_global_load_lds((const __attribute__((address_space(1))) void*)(ta + e),
                                       (__attribute__((address_space(3))) void*)(sa + e), 16, 0, 0);
      __builtin_amdgcn_global_load_lds((const __attribute__((address_space(1))) void*)(tb + e),
                                       (__attribute__((address_space(3))) void*)(sb + e), 16, 0, 0);
    }
    __syncthreads();
#pragma unroll
    for (int ks = 0; ks < 2; ++ks) {
      f16x8 af[2], bf[8];
#pragma unroll
      for (int tr = 0; tr < 2; ++tr)
        af[tr] = *(const f16x8*)(sa + ((ks * 8 + w * 2 + tr) * 64 + l) * 8);
#pragma unroll
      for (int tc = 0; tc < 8; ++tc)
        bf[tc] = *(const f16x8*)(sb + ((ks * 8 + tc) * 64 + l) * 8);
#pragma unroll
      for (int tr = 0; tr < 2; ++tr)
#pragma unroll
        for (int tc = 0; tc < 8; ++tc)
          acc[tr][tc] = __builtin_amdgcn_mfma_f32_16x16x32_f16(af[tr], bf[tc], acc[tr][tc], 0, 0, 0);
    }
  }
  // epilogue scatter
#pragma unroll
  for (int tr = 0; tr < 2; ++tr)
#pragma unroll
    for (int tc = 0; tc < 8; ++tc)
#pragma unroll
      for (int r = 0; r < 4; ++r) {
        int row = by * 128 + w * 32 + tr * 16 + q * 4 + r;
        int col = bx * 128 + tc * 16 + c;
        float v = acc[tr][tc][r];
        int t = col >> 10, head = (col >> 6) & 15, dh = col & 63;
        if (t == 0 || t == 3) v *= 0.125f;
        f16 hv = (f16)v;
        if (t == 4) {
          size_t addr = (size_t)4 * NHSD + (size_t)head * (SEQ * DH) + ((size_t)(row >> 7) << 13)
                      + (size_t)(((((dh >> 5) << 3) + ((row >> 4) & 7)) * 64
                                  + ((((dh >> 3) & 3) << 4) | (row & 15))) * 8 + (dh & 7));
          q6[addr] = hv;
        } else if (t == 5) {
          size_t addr = (size_t)5 * NHSD + (size_t)head * (SEQ * DH) + ((size_t)(row >> 7) << 13)
                      + (size_t)((((((row >> 5) & 3) << 2) + (dh >> 4)) * 64
                                  + ((((row >> 3) & 3) << 4) | (dh & 15))) * 8 + (row & 7));
          q6[addr] = hv;
        } else if (t == 2) {
          q6[(size_t)2 * NHSD + (size_t)(head * SEQ + row) * DH + dh] = hv;
          size_t fa = ((size_t)(row >> 7) << 13)
                    + (size_t)((((((row >> 5) & 3) << 2) + (dh >> 4)) * 64
                                + ((((row >> 3) & 3) << 4) | (dh & 15))) * 8 + (row & 7));
          vuF[(size_t)head * (SEQ * DH) + fa] = hv;
        } else {
          q6[(size_t)t * NHSD + (size_t)(head * SEQ + row) * DH + dh] = hv;
        }
      }
}

// ---------------- tile producer: t1 DIAGONAL tiles only (16/head) + all lk tiles ----------------
__global__ __launch_bounds__(256) void k_t1lk(const f16* __restrict__ q6, f16* __restrict__ t1dT,
                                              f16* __restrict__ lkT) {
  __shared__ f16 st[128 * 128];
  int head = blockIdx.x / 152;
  int p = blockIdx.x % 152;
  bool is_lk = (p >= 16);
  int RB, CB;
  f16* dst;
  if (is_lk) {
    int p2 = p - 16;
    int K = 0, off = 0;
    while (off + (16 - K) <= p2) { off += 16 - K; ++K; }
    RB = K; CB = K + (p2 - off);
    dst = lkT + ((size_t)(head * NTILE + p2) << 14);
  } else {
    RB = p; CB = p;   // diagonal t1 tile
    dst = t1dT + ((size_t)(head * 16 + p) << 14);
  }
  const f16* Ah = q6 + (size_t)(is_lk ? 0 : 3) * NHSD + (size_t)head * SEQ * DH;  // qu_s / qc_s
  const f16* Bh = q6 + (size_t)(is_lk ? 1 : 2) * NHSD + (size_t)head * SEQ * DH;  // ku / vu
  int tid = threadIdx.x, w = tid >> 6, l = tid & 63, q = l >> 4, c = l & 15;
  const f32x4 zf = {0.f, 0.f, 0.f, 0.f};
  f32x4 tacc[2][8];
  for (int tr = 0; tr < 2; ++tr) for (int tc = 0; tc < 8; ++tc) tacc[tr][tc] = zf;
#pragma unroll
  for (int ks = 0; ks < 2; ++ks) {
    f16x8 aq[2], bf[8];
#pragma unroll
    for (int tr = 0; tr < 2; ++tr)
      aq[tr] = *(const f16x8*)(Ah + (size_t)(RB * 128 + w * 32 + tr * 16 + c) * DH + ks * 32 + q * 8);
#pragma unroll
    for (int tc = 0; tc < 8; ++tc)
      bf[tc] = *(const f16x8*)(Bh + (size_t)(CB * 128 + tc * 16 + c) * DH + ks * 32 + q * 8);
#pragma unroll
    for (int tr = 0; tr < 2; ++tr)
#pragma unroll
      for (int tc = 0; tc < 8; ++tc)
        tacc[tr][tc] = __builtin_amdgcn_mfma_f32_16x16x32_f16(aq[tr], bf[tc], tacc[tr][tc], 0, 0, 0);
  }
#pragma unroll
  for (int tr = 0; tr < 2; ++tr)
#pragma unroll
    for (int tc = 0; tc < 8; ++tc)
#pragma unroll
      for (int r = 0; r < 4; ++r) {
        int row = w * 32 + tr * 16 + q * 4 + r;
        int col = tc * 16 + c;
        int rg = RB * 128 + row, cg = CB * 128 + col;
        float v = tacc[tr][tc][r];
        f16 ov;
        if (is_lk) ov = (cg > rg) ? (f16)__builtin_amdgcn_rcpf(1.f + __expf(-v)) : (f16)(0.f);
        else       ov = (cg <= rg) ? (f16)v : (f16)(0.f);
        st[(row << 7) + (((col >> 3) ^ (row & 15)) << 3) + (col & 7)] = ov;
      }
  __syncthreads();
#pragma unroll
  for (int i = 0; i < 8; ++i) {
    int ch = i * 256 + tid;
    int ks = ch >> 9, rb = (ch >> 6) & 7, ln = ch & 63;
    int qq = ln >> 4, cc = ln & 15;
    int row = rb * 16 + cc, cchunk = ks * 4 + qq;
    f16x8 v = *(const f16x8*)(st + (row << 7) + ((cchunk ^ (row & 15)) << 3));
    *(f16x8*)(dst + (size_t)ch * 8) = v;
  }
}

// ---------------- prefix kernel: PP(K,J) = sum_{J'=K..J} lkT(K,J') @ vu(J') ----------------
// Double-buffered staging (lkb[2]+vub[2]+st = 112KB LDS).
__global__ __launch_bounds__(256) void k_prefix(const f16* __restrict__ lkT, const f16* __restrict__ vuF,
                                                f16* __restrict__ PPT) {
  __shared__ f16 lkb[2][16384];
  __shared__ f16 vub[2][8192];
  __shared__ f16 st[8192];
  int head = blockIdx.x >> 4, K = blockIdx.x & 15;
  int offK = 16 * K - (K * (K - 1)) / 2;
  const f16* lkh = lkT + ((size_t)(head * NTILE) << 14);
  const f16* vuh = vuF + (size_t)head * (SEQ * DH);
  f16* pph = PPT + ((size_t)(head * NTILE) << 13);
  int tid = threadIdx.x, w = tid >> 6, l = tid & 63, q = l >> 4, c = l & 15;
  f32x4 acc[2][4];
  const f32x4 zf = {0.f, 0.f, 0.f, 0.f};
  for (int tr = 0; tr < 2; ++tr) for (int tv = 0; tv < 4; ++tv) acc[tr][tv] = zf;
  // prologue: stage J=K into buf 0
  {
    const f16* lt = lkh + ((size_t)offK << 14);
#pragma unroll
    for (int i = 0; i < 8; ++i) {
      int e = (i * 256 + tid) * 8;
      __builtin_amdgcn_global_load_lds((const __attribute__((address_space(1))) void*)(lt + e),
                                       (__attribute__((address_space(3))) void*)(&lkb[0][0] + e), 16, 0, 0);
    }
    const f16* vt_ = vuh + ((size_t)K << 13);
#pragma unroll
    for (int i = 0; i < 4; ++i) {
      int e = (i * 256 + tid) * 8;
      __builtin_amdgcn_global_load_lds((const __attribute__((address_space(1))) void*)(vt_ + e),
                                       (__attribute__((address_space(3))) void*)(&vub[0][0] + e), 16, 0, 0);
    }
  }
  int pb = 0;
  for (int J = K; J < 16; ++J) {
    __syncthreads();   // buf[pb] staged; previous st re-reads complete
    if (J < 15) {      // prefetch next J into the idle buffer (overlaps MFMA + st phases)
      const f16* lt = lkh + ((size_t)(offK + (J + 1 - K)) << 14);
#pragma unroll
      for (int i = 0; i < 8; ++i) {
        int e = (i * 256 + tid) * 8;
        __builtin_amdgcn_global_load_lds((const __attribute__((address_space(1))) void*)(lt + e),
                                         (__attribute__((address_space(3))) void*)(&lkb[pb ^ 1][0] + e), 16, 0, 0);
      }
      const f16* vt_ = vuh + ((size_t)(J + 1) << 13);
#pragma unroll
      for (int i = 0; i < 4; ++i) {
        int e = (i * 256 + tid) * 8;
        __builtin_amdgcn_global_load_lds((const __attribute__((address_space(1))) void*)(vt_ + e),
                                         (__attribute__((address_space(3))) void*)(&vub[pb ^ 1][0] + e), 16, 0, 0);
      }
    }
#pragma unroll
    for (int ks = 0; ks < 4; ++ks) {
      f16x8 af[2], bf[4];
#pragma unroll
      for (int tr = 0; tr < 2; ++tr)
        af[tr] = *(const f16x8*)(&lkb[pb][0] + ((ks * 8 + w * 2 + tr) * 64 + l) * 8);
#pragma unroll
      for (int tv = 0; tv < 4; ++tv)
        bf[tv] = *(const f16x8*)(&vub[pb][0] + ((ks * 4 + tv) * 64 + l) * 8);
#pragma unroll
      for (int tr = 0; tr < 2; ++tr)
#pragma unroll
        for (int tv = 0; tv < 4; ++tv)
          acc[tr][tv] = __builtin_amdgcn_mfma_f32_16x16x32_f16(af[tr], bf[tv], acc[tr][tv], 0, 0, 0);
    }
    // acc -> st (f16, swizzled 128x64)
#pragma unroll
    for (int tr = 0; tr < 2; ++tr)
#pragma unroll
      for (int tv = 0; tv < 4; ++tv)
#pragma unroll
        for (int r = 0; r < 4; ++r) {
          int row = w * 32 + tr * 16 + q * 4 + r;
          int col = tv * 16 + c;
          st[(row << 6) + (((col >> 3) ^ (row & 7)) << 3) + (col & 7)] = (f16)acc[tr][tv][r];
        }
    __syncthreads();   // st complete (prefetch had the MFMA phase to fly)
    // st re-read in frag order -> PPT(K,J)
    f16* dst = pph + ((size_t)(offK + (J - K)) << 13);
#pragma unroll
    for (int i = 0; i < 4; ++i) {
      int slot = i * 256 + tid;
      int chunk = slot >> 6, ln = slot & 63;
      int ks2 = chunk >> 3, tc = chunk & 7, qq = ln >> 4, cc = ln & 15;
      int row = tc * 16 + cc, cch = ks2 * 4 + qq;
      f16x8 v = *(const f16x8*)(st + (row << 6) + ((cch ^ (row & 7)) << 3));
      *(f16x8*)(dst + (size_t)slot * 8) = v;
    }
    pb ^= 1;
  }
}

// ---------------- flash (R25 structure, unchanged): R24 pipeline + 8 waves x 16 rows ----------------
__global__ __launch_bounds__(512, 1) void k_flash(const f16* __restrict__ q6, const f16* __restrict__ t1dT,
                                                  const f16* __restrict__ lkT, const f16* __restrict__ PPT,
                                                  f16* __restrict__ pO, float* __restrict__ pML) {
  __shared__ f16 Sb[2][40960];      // 2 x 80KB: each = lk(0) | pp(16384) | kc(24576) | vt(32768)
  int bid = blockIdx.x;
  int big = bid & 1;
  int rest = bid >> 1;
  int head = ((rest & 7) << 1) | ((rest >> 3) & 1);
  int r2 = 31 - (rest >> 4);        // reversed: big pairs dispatch first
  int a = 0, s = 0;
  {
    int acc = 0;
    for (int aa = 0; aa < 8; ++aa) {
      int si = ns2(aa);
      if (r2 >= acc && r2 < acc + si) { a = aa; s = r2 - acc; }
      acc += si;
    }
  }
  int I1 = 2 * a + 1;
  int S_ = ns2(a);
  int Ktot = I1 + 1;
  int K0 = (Ktot * s) / S_, K1 = (Ktot * (s + 1)) / S_;
  int IB = 2 * a + big;             // this block's I-tile
  int Kbeg = (K0 < IB + 1) ? K0 : IB + 1;
  int Kend = (K1 < IB + 1) ? K1 : IB + 1;

  const f16* qc  = q6 + (size_t)3 * NHSD + (size_t)head * SEQ * DH;   // pre-scaled
  const f16* kcF = q6 + (size_t)4 * NHSD + (size_t)head * (SEQ * DH);
  const f16* vtF = q6 + (size_t)5 * NHSD + (size_t)head * (SEQ * DH);
  int tid = threadIdx.x, w = tid >> 6, l = tid & 63, q = l >> 4, c = l & 15;
  const f16* lkh = lkT + ((size_t)(head * NTILE) << 14);
  const f16* pph = PPT + ((size_t)(head * NTILE) << 13);
  const f16* t1d = t1dT + ((size_t)(head * 16 + IB) << 14);

  // per-wave constants in registers (wave w owns rows [w*16, w*16+16))
  f16x8 a_qc[2];
#pragma unroll
  for (int ks = 0; ks < 2; ++ks)
    a_qc[ks] = *(const f16x8*)(qc + (size_t)(IB * 128 + w * 16 + c) * DH + ks * 32 + q * 8);
  f16x8 a_t1[4];
#pragma unroll
  for (int ks = 0; ks < 4; ++ks)
    a_t1[ks] = *(const f16x8*)(t1d + (size_t)((ks * 8 + w) * 64 + l) * 8);

  f32x4 su[8], oacc[4];
  float m_i[4], l_i[4];
  const f32x4 zf = {0.f, 0.f, 0.f, 0.f};
  for (int tv = 0; tv < 4; ++tv) oacc[tv] = zf;
  for (int r = 0; r < 4; ++r) { m_i[r] = -INFINITY; l_i[r] = 0.f; }

  // prologue: stage K=Kbeg into buf 0
  if (Kbeg < Kend) {
    int K = Kbeg;
    int offK = 16 * K - (K * (K - 1)) / 2;
    f16* D = &Sb[0][0];
    const f16* p1 = lkh + ((size_t)(offK + (IB - K)) << 14);
#pragma unroll
    for (int i = 0; i < 4; ++i) {
      int e = (i * 512 + tid) * 8;
      __builtin_amdgcn_global_load_lds((const __attribute__((address_space(1))) void*)(p1 + e),
                                       (__attribute__((address_space(3))) void*)(D + e), 16, 0, 0);
    }
    if (K < IB) {
      const f16* pp = pph + ((size_t)(offK + (IB - 1 - K)) << 13);
#pragma unroll
      for (int i = 0; i < 2; ++i) {
        int e = (i * 512 + tid) * 8;
        __builtin_amdgcn_global_load_lds((const __attribute__((address_space(1))) void*)(pp + e),
                                         (__attribute__((address_space(3))) void*)(D + 16384 + e), 16, 0, 0);
      }
    }
    const f16* kt_ = kcF + ((size_t)K << 13);
    const f16* vv_ = vtF + ((size_t)K << 13);
#pragma unroll
    for (int i = 0; i < 2; ++i) {
      int e = (i * 512 + tid) * 8;
      __builtin_amdgcn_global_load_lds((const __attribute__((address_space(1))) void*)(kt_ + e),
                                       (__attribute__((address_space(3))) void*)(D + 24576 + e), 16, 0, 0);
      __builtin_amdgcn_global_load_lds((const __attribute__((address_space(1))) void*)(vv_ + e),
                                       (__attribute__((address_space(3))) void*)(D + 32768 + e), 16, 0, 0);
    }
  }

  int cur = 0;
  for (int K = Kbeg; K < Kend; ++K) {
#pragma unroll
    for (int tc = 0; tc < 8; ++tc) su[tc] = zf;

    __syncthreads();   // top: buf[cur]'s stage drained; prior PV reads of buf[cur^1] ordered

    // issue next-K stage into buf[cur^1] — flies through the entire compute phase
    if (K + 1 < Kend) {
      int Kn = K + 1;
      int offKn = 16 * Kn - (Kn * (Kn - 1)) / 2;
      f16* D = &Sb[cur ^ 1][0];
      const f16* p1 = lkh + ((size_t)(offKn + (IB - Kn)) << 14);
#pragma unroll
      for (int i = 0; i < 4; ++i) {
        int e = (i * 512 + tid) * 8;
        __builtin_amdgcn_global_load_lds((const __attribute__((address_space(1))) void*)(p1 + e),
                                         (__attribute__((address_space(3))) void*)(D + e), 16, 0, 0);
      }
      if (Kn < IB) {
        const f16* pp = pph + ((size_t)(offKn + (IB - 1 - Kn)) << 13);
#pragma unroll
        for (int i = 0; i < 2; ++i) {
          int e = (i * 512 + tid) * 8;
          __builtin_amdgcn_global_load_lds((const __attribute__((address_space(1))) void*)(pp + e),
                                           (__attribute__((address_space(3))) void*)(D + 16384 + e), 16, 0, 0);
        }
      }
      const f16* kt_ = kcF + ((size_t)Kn << 13);
      const f16* vv_ = vtF + ((size_t)Kn << 13);
#pragma unroll
      for (int i = 0; i < 2; ++i) {
        int e = (i * 512 + tid) * 8;
        __builtin_amdgcn_global_load_lds((const __attribute__((address_space(1))) void*)(kt_ + e),
                                         (__attribute__((address_space(3))) void*)(D + 24576 + e), 16, 0, 0);
        __builtin_amdgcn_global_load_lds((const __attribute__((address_space(1))) void*)(vv_ + e),
                                         (__attribute__((address_space(3))) void*)(D + 32768 + e), 16, 0, 0);
      }
    }

    f16* bufc = &Sb[cur][0];
    // PP term: su += a_qc @ PP(K, IB-1)
    if (K < IB) {
      const f16* ppb = bufc + 16384;
#pragma unroll
      for (int ks = 0; ks < 2; ++ks) {
        f16x8 bf[8];
#pragma unroll
        for (int tc = 0; tc < 8; ++tc)
          bf[tc] = *(const f16x8*)(ppb + ((ks * 8 + tc) * 64 + l) * 8);
#pragma unroll
        for (int tc = 0; tc < 8; ++tc)
          su[tc] = __builtin_amdgcn_mfma_f32_16x16x32_f16(a_qc[ks], bf[tc], su[tc], 0, 0, 0);
      }
    }
    // t1d term: su += a_t1 @ lk(K, IB)^T
    {
      __builtin_amdgcn_s_setprio(1);
#pragma unroll
      for (int ks = 0; ks < 4; ++ks) {
        f16x8 bf[8];
#pragma unroll
        for (int tc = 0; tc < 8; ++tc)
          bf[tc] = *(const f16x8*)(bufc + ((ks * 8 + tc) * 64 + l) * 8);
#pragma unroll
        for (int tc = 0; tc < 8; ++tc)
          su[tc] = __builtin_amdgcn_mfma_f32_16x16x32_f16(a_t1[ks], bf[tc], su[tc], 0, 0, 0);
      }
      __builtin_amdgcn_s_setprio(0);
    }
    // scores = Sc - silu(Su)
#pragma unroll
    for (int tc = 0; tc < 8; ++tc)
#pragma unroll
      for (int r = 0; r < 4; ++r) {
        float v = su[tc][r];
        su[tc][r] = -v * __builtin_amdgcn_rcpf(1.f + __expf(-v));
      }
    {
      const f16* skc = bufc + 24576;
#pragma unroll
      for (int ks = 0; ks < 2; ++ks) {
        f16x8 bk[8];
#pragma unroll
        for (int tc = 0; tc < 8; ++tc)
          bk[tc] = *(const f16x8*)(skc + ((ks * 8 + tc) * 64 + l) * 8);
#pragma unroll
        for (int tc = 0; tc < 8; ++tc)
          su[tc] = __builtin_amdgcn_mfma_f32_16x16x32_f16(a_qc[ks], bk[tc], su[tc], 0, 0, 0);
      }
    }
    if (K == IB) {     // strict causal mask on the diagonal block
#pragma unroll
      for (int tc = 0; tc < 8; ++tc)
#pragma unroll
        for (int r = 0; r < 4; ++r) {
          int rg = w * 16 + q * 4 + r;
          int cg = tc * 16 + c;
          if (cg > rg) su[tc][r] = -INFINITY;
        }
    }
    // online softmax
#pragma unroll
    for (int r = 0; r < 4; ++r) {
      float mx = su[0][r];
#pragma unroll
      for (int tc = 1; tc < 8; ++tc) mx = fmaxf(mx, su[tc][r]);
      mx = fmaxf(mx, __shfl_xor(mx, 1)); mx = fmaxf(mx, __shfl_xor(mx, 2));
      mx = fmaxf(mx, __shfl_xor(mx, 4)); mx = fmaxf(mx, __shfl_xor(mx, 8));
      float mnew  = fmaxf(m_i[r], mx);
      float alpha = __expf(m_i[r] - mnew);
      float ssum = 0.f;
#pragma unroll
      for (int tc = 0; tc < 8; ++tc) {
        float pp = __expf(su[tc][r] - mnew);
        su[tc][r] = pp;
        ssum += pp;
      }
      ssum += __shfl_xor(ssum, 1); ssum += __shfl_xor(ssum, 2);
      ssum += __shfl_xor(ssum, 4); ssum += __shfl_xor(ssum, 8);
      l_i[r] = l_i[r] * alpha + ssum;
      m_i[r] = mnew;
#pragma unroll
      for (int tv = 0; tv < 4; ++tv) oacc[tv][r] *= alpha;
    }
    // join barrier: lgkmcnt-only (keeps next-K stage in flight). Orders all waves' lk/pp/kc
    // ds_reads before the P writes into bufc's lk region.
    asm volatile("s_waitcnt lgkmcnt(0)" ::: "memory");
    __builtin_amdgcn_sched_barrier(0);
    __builtin_amdgcn_s_barrier();
    __builtin_amdgcn_sched_barrier(0);
    // P -> Pb (= bufc lk region; own 16-row region of the 128-row buffer)
#pragma unroll
    for (int tc = 0; tc < 8; ++tc)
#pragma unroll
      for (int r = 0; r < 4; ++r) {
        int row = w * 16 + q * 4 + r;    // 0..127
        int col = tc * 16 + c;
        bufc[(row << 7) + (((col >> 3) ^ (row & 15)) << 3) + (col & 7)] = (f16)su[tc][r];
      }
    // PV: A = P (own rows), B = staged vt
    {
      const f16* svt = bufc + 32768;
#pragma unroll
      for (int ks = 0; ks < 4; ++ks) {
        int ck = ks * 4 + q;
        f16x8 ap, bv[4];
        ap = *(const f16x8*)(bufc + ((w * 16 + c) << 7) + ((ck ^ c) << 3));
#pragma unroll
        for (int tv = 0; tv < 4; ++tv)
          bv[tv] = *(const f16x8*)(svt + ((ks * 4 + tv) * 64 + l) * 8);
#pragma unroll
        for (int tv = 0; tv < 4; ++tv)
          oacc[tv] = __builtin_amdgcn_mfma_f32_16x16x32_f16(ap, bv[tv], oacc[tv], 0, 0, 0);
      }
    }
    cur ^= 1;
  }

  // ---- unnormalized partial: slot = head*64 + prefix(IB) + s (empty ranges write m=-inf) ----
  int slot = head * SLOTS_PER_HEAD + slot_base(IB) + s;
  f16* po = pO + (size_t)slot * (128 * 64);
  float* pml = pML + (size_t)slot * 256;
  if (c == 0) {
#pragma unroll
    for (int r = 0; r < 4; ++r) {
      int row = w * 16 + q * 4 + r;
      pml[row] = m_i[r];
      pml[128 + row] = l_i[r];
    }
  }
#pragma unroll
  for (int tv = 0; tv < 4; ++tv)
#pragma unroll
    for (int r = 0; r < 4; ++r) {
      int row = w * 16 + q * 4 + r;
      int col = tv * 16 + c;
      po[row * 64 + col] = (f16)oacc[tv][r];
    }
}

// ---------------- merge partials -> oh [2048][1024] f16 ----------------
__global__ __launch_bounds__(256) void k_merge(const f16* __restrict__ pO, const float* __restrict__ pML,
                                               f16* __restrict__ oh) {
  int head = blockIdx.x >> 4, I = blockIdx.x & 15;
  int S_ = ns2(I >> 1);
  int tid = threadIdx.x;
  int row = tid >> 1, half = tid & 1;
  int base = head * SLOTS_PER_HEAD + slot_base(I);
  float m[MAXS], lv[MAXS];
  float mstar = -INFINITY;
#pragma unroll
  for (int s = 0; s < MAXS; ++s)
    if (s < S_) {
      m[s] = pML[(size_t)(base + s) * 256 + row];
      lv[s] = pML[(size_t)(base + s) * 256 + 128 + row];
      mstar = fmaxf(mstar, m[s]);
    }
  float wt[MAXS];
  float lsum = 0.f;
#pragma unroll
  for (int s = 0; s < MAXS; ++s)
    if (s < S_) {
      wt[s] = __expf(m[s] - mstar);   // empty partials (m=-inf) get weight 0
      lsum += lv[s] * wt[s];
    }
  float rinv = __builtin_amdgcn_rcpf(lsum);
#pragma unroll
  for (int cc = 0; cc < 32; cc += 8) {
    float acc[8] = {0.f, 0.f, 0.f, 0.f, 0.f, 0.f, 0.f, 0.f};
#pragma unroll
    for (int s = 0; s < MAXS; ++s)
      if (s < S_) {
        f16x8 v = *(const f16x8*)(pO + (size_t)(base + s) * 8192 + row * 64 + half * 32 + cc);
#pragma unroll
        for (int e = 0; e < 8; ++e) acc[e] += wt[s] * (float)v[e];
      }
    f16x8 o;
#pragma unroll
    for (int e = 0; e < 8; ++e) o[e] = (f16)(acc[e] * rinv);
    *(f16x8*)(oh + (size_t)(I * 128 + row) * DIM + head * 64 + half * 32 + cc) = o;
  }
}

// ---------------- final GEMM (R26: 128x64 tiles, grid (16,16) -> 256 blocks, 1/CU) ----------------
// R25 profile hinted gemm_out is latency-bound with only 128 blocks on 256 CUs. Halve the output
// tile width: per-block B-tile 64 rows, acc[2][4]; same K-order per output element (bit-identical).
__global__ __launch_bounds__(256) void k_gemm_out(const f16* __restrict__ A, const f16* __restrict__ B,
                                                  float* __restrict__ out) {
  __shared__ f16 sa[128 * 72];
  __shared__ f16 sb[64 * 72];
  int bx = blockIdx.x, by = blockIdx.y;
  int tid = threadIdx.x, w = tid >> 6, l = tid & 63, q = l >> 4, c = l & 15;
  f32x4 acc[2][4];
  const f32x4 zf = {0.f, 0.f, 0.f, 0.f};
  for (int i = 0; i < 2; ++i) for (int j = 0; j < 4; ++j) acc[i][j] = zf;
  for (int kt = 0; kt < DIM / 64; ++kt) {
    __syncthreads();
#pragma unroll
    for (int it = 0; it < 4; ++it) {
      int idx = it * 256 + tid; int r = idx >> 3, ch = idx & 7;
      *(float4*)(sa + r * 72 + ch * 8) = *(const float4*)(A + (size_t)(by * 128 + r) * DIM + kt * 64 + ch * 8);
    }
#pragma unroll
    for (int it = 0; it < 2; ++it) {
      int idx = it * 256 + tid; int r = idx >> 3, ch = idx & 7;
      *(float4*)(sb + r * 72 + ch * 8) = *(const float4*)(B + (size_t)(bx * 64 + r) * DIM + kt * 64 + ch * 8);
    }
    __syncthreads();
#pragma unroll
    for (int ks = 0; ks < 2; ++ks) {
      f16x8 af[2], bf[4];
#pragma unroll
      for (int tr = 0; tr < 2; ++tr) af[tr] = *(const f16x8*)(sa + (w * 32 + tr * 16 + c) * 72 + ks * 32 + q * 8);
#pragma unroll
      for (int tc = 0; tc < 4; ++tc) bf[tc] = *(const f16x8*)(sb + (tc * 16 + c) * 72 + ks * 32 + q * 8);
#pragma unroll
      for (int tr = 0; tr < 2; ++tr)
#pragma unroll
        for (int tc = 0; tc < 4; ++tc)
          acc[tr][tc] = __builtin_amdgcn_mfma_f32_16x16x32_f16(af[tr], bf[tc], acc[tr][tc], 0, 0, 0);
    }
  }
#pragma unroll
  for (int tr = 0; tr < 2; ++tr)
#pragma unroll
    for (int tc = 0; tc < 4; ++tc)
#pragma unroll
      for (int r = 0; r < 4; ++r) {
        int row = by * 128 + w * 32 + tr * 16 + q * 4 + r;
        int col = bx * 64 + tc * 16 + c;
        out[(size_t)row * DIM + col] = acc[tr][tc][r];
      }
}

extern "C" void kernel_launch(void* const* d_in, const int* in_sizes, int n_in,
                              void* d_out, int out_size, void* d_ws, size_t ws_size,
                              hipStream_t stream) {
  const float* x  = (const float*)d_in[0];
  const float* Wq = (const float*)d_in[1];
  const float* Wo = (const float*)d_in[2];
  float* out = (float*)d_out;

  f16* ws = (f16*)d_ws;
  size_t off = 0;
  f16* q6   = ws + off; off += (size_t)6 * NHSD;                        // 25.2 MB
  f16* vuF  = ws + off; off += (size_t)NHSD;                            // 4.2 MB (vu^T frag tiles)
  f16* xhT  = ws + off; off += (size_t)SEQ * DIM;                       // 4.2 MB
  f16* WqTf = ws + off; off += (size_t)NCOLS * DIM;                     // 12.6 MB
  f16* WoT  = ws + off; off += (size_t)DIM * DIM;                       // 2.1 MB
  f16* oh   = ws + off; off += (size_t)SEQ * DIM;                       // 4.2 MB
  f16* pO   = ws + off; off += (size_t)NH * SLOTS_PER_HEAD * 128 * 64;  // 16.8 MB
  f16* lkT  = ws + off; off += (size_t)NH * NTILE * 128 * 128;          // 71.3 MB
  f16* t1dT = ws + off; off += (size_t)NH * 16 * 128 * 128;             // 8.4 MB (diag t1 only)
  f16* PPT  = ws + off; off += (size_t)NH * NTILE * 128 * 64;           // 35.7 MB (prefix tiles)
  float* pML = (float*)(ws + off); off += (size_t)NH * SLOTS_PER_HEAD * 256 * 2; // 1.05 MB
  // total ~186 MB of workspace

  k_prep<<<1280, 256, 0, stream>>>(x, xhT, Wq, WqTf, Wo, WoT);
  k_gemm_qkv<<<dim3(NCOLS / 128, SEQ / 128), 256, 0, stream>>>(xhT, WqTf, q6, vuF);
  k_t1lk<<<NH * 152, 256, 0, stream>>>(q6, t1dT, lkT);
  k_prefix<<<NH * 16, 256, 0, stream>>>(lkT, vuF, PPT);
  k_flash<<<NH * 64, 512, 0, stream>>>(q6, t1dT, lkT, PPT, pO, pML);
  k_merge<<<NH * 16, 256, 0, stream>>>(pO, pML, oh);
  k_gemm_out<<<dim3(DIM / 64, SEQ / 128), 256, 0, stream>>>(oh, WoT, out);
}

// Round 13
// 331.391 us; speedup vs baseline: 1.0181x; 1.0181x over previous
//
#include <hip/hip_runtime.h>
#include <math.h>

typedef _Float16 f16;
typedef _Float16 f16x4 __attribute__((ext_vector_type(4)));
typedef _Float16 f16x8 __attribute__((ext_vector_type(8)));
typedef float f32x4 __attribute__((ext_vector_type(4)));

#define SEQ   2048
#define DIM   1024
#define NH    16
#define DH    64
#define NCOLS 6144
#define NHSD  (NH*SEQ*DH)   /* 2,097,152 elements per qkv sub-tensor */
#define NTILE 136           /* lk tiles per head (triangular) */
#define MAXS  9
#define SLOTS_PER_HEAD 64   /* sum over I of NS2[I>>1] */

// pair-splits: pair a = (I0=2a, I1=2a+1); NS2 K-splits per pair.
__device__ __forceinline__ int ns2(int a) {
  const int NS2[8] = {1,1,2,3,4,5,7,9};
  return NS2[a];
}
__device__ __forceinline__ int slot_base(int I) {  // prefix of NS2[I'>>1] over I' < I
  const int PF[16] = {0,1,2,3,4,6,8,11,14,18,22,27,32,39,46,55};
  return PF[I];
}

// ---------------- fused prep: prepA (256 blocks) | prepB (768) | tcast (256) ----------------
__global__ __launch_bounds__(256) void k_prep(const float* __restrict__ x,  f16* __restrict__ xhT,
                                              const float* __restrict__ Wq, f16* __restrict__ WqTf,
                                              const float* __restrict__ Wo, f16* __restrict__ WoT) {
  __shared__ f16 sw[64 * 130];
  int b = blockIdx.x;
  int tid = threadIdx.x;
  if (b < 256) {
    // ---- prepA: x (f32) -> A-frag-chunk tiles (already coalesced) ----
    int kt = b & 15, by = b >> 4;
    f16* dst = xhT + ((size_t)(by * 16 + kt) << 13);
#pragma unroll
    for (int i = 0; i < 4; ++i) {
      int idx = i * 256 + tid;
      int chunk = idx >> 6, lane = idx & 63;
      int rb = chunk & 7, ks = chunk >> 3;
      int row = by * 128 + rb * 16 + (lane & 15);
      int kk = kt * 64 + ks * 32 + ((lane >> 4) << 3);
      const float* p = x + (size_t)row * DIM + kk;
      float4 lo = *(const float4*)p, hi = *(const float4*)(p + 4);
      f16x8 h;
      h[0] = (f16)lo.x; h[1] = (f16)lo.y; h[2] = (f16)lo.z; h[3] = (f16)lo.w;
      h[4] = (f16)hi.x; h[5] = (f16)hi.y; h[6] = (f16)hi.z; h[7] = (f16)hi.w;
      *(f16x8*)(dst + (size_t)idx * 8) = h;
    }
  } else if (b < 1024) {
    // ---- prepB: Wq[k][n] -> B-frag-chunk tiles via LDS transpose ----
    int t = b - 256;
    int kt = t & 15, bx = t >> 4;
#pragma unroll
    for (int it = 0; it < 8; ++it) {
      int idx = it * 256 + tid;          // 0..2047
      int r = idx >> 5, c4 = idx & 31;   // row, float4-chunk
      float4 v = *(const float4*)(Wq + (size_t)(kt * 64 + r) * NCOLS + bx * 128 + c4 * 4);
      f16* d = sw + r * 130 + c4 * 4;
      d[0] = (f16)v.x; d[1] = (f16)v.y; d[2] = (f16)v.z; d[3] = (f16)v.w;
    }
    __syncthreads();
    f16* dst = WqTf + ((size_t)(bx * 16 + kt) << 13);
#pragma unroll
    for (int i = 0; i < 4; ++i) {
      int idx = i * 256 + tid;
      int chunk = idx >> 6, lane = idx & 63;
      int rb = chunk & 7, ks = chunk >> 3;
      int nl = rb * 16 + (lane & 15);
      int kl = ks * 32 + ((lane >> 4) << 3);
      f16x8 h;
#pragma unroll
      for (int j = 0; j < 8; ++j) h[j] = sw[(kl + j) * 130 + nl];
      *(f16x8*)(dst + (size_t)idx * 8) = h;
    }
  } else {
    // ---- tcast: WoT[c][r] = (f16) Wo[r][c] ----
    int t = b - 1024;
    int bc = t & 15, br = t >> 4;
    for (int it = 0; it < 16; ++it) {
      int idx = it * 256 + tid;
      int r = idx >> 6, c = idx & 63;
      sw[r * 66 + c] = (f16)Wo[(size_t)(br * 64 + r) * DIM + bc * 64 + c];
    }
    __syncthreads();
    for (int it = 0; it < 16; ++it) {
      int idx = it * 256 + tid;
      int oc = idx >> 6, orr = idx & 63;
      WoT[(size_t)(bc * 64 + oc) * DIM + br * 64 + orr] = sw[orr * 66 + oc];
    }
  }
}

// ---------------- qkv GEMM (R27: double-buffered K-pipeline, one barrier per step) ----------------
// R26 profile: 93us, MfmaUtil 11%, both pipes low -> the single-buffered 2-barrier loop exposes
// the full 32KB stage every K-step. R24's proven pattern: top __syncthreads drains last iter's
// stage AND orders prior reads of the buffer about to be overwritten; issue next-K stage into the
// idle buffer immediately; MFMA from current buffer while the stage flies. 64KB LDS, 2 blocks/CU.
__global__ __launch_bounds__(256) void k_gemm_qkv(const f16* __restrict__ xhT, const f16* __restrict__ WqTf,
                                                  f16* __restrict__ q6, f16* __restrict__ vuF) {
  __shared__ f16 sa[2][8192];
  __shared__ f16 sb[2][8192];
  int bx = blockIdx.x, by = blockIdx.y;
  int tid = threadIdx.x, w = tid >> 6, l = tid & 63, q = l >> 4, c = l & 15;
  f32x4 acc[2][8];
  const f32x4 zf = {0.f, 0.f, 0.f, 0.f};
  for (int i = 0; i < 2; ++i) for (int j = 0; j < 8; ++j) acc[i][j] = zf;

  // prologue: stage kt=0 into buf 0
  {
    const f16* ta = xhT + ((size_t)(by * 16) << 13);
    const f16* tb = WqTf + ((size_t)(bx * 16) << 13);
#pragma unroll
    for (int i = 0; i < 4; ++i) {
      int e = (i * 256 + tid) * 8;
      __builtin_amdgcn_global_load_lds((const __attribute__((address_space(1))) void*)(ta + e),
                                       (__attribute__((address_space(3))) void*)(&sa[0][0] + e), 16, 0, 0);
      __builtin_amdgcn_global_load_lds((const __attribute__((address_space(1))) void*)(tb + e),
                                       (__attribute__((address_space(3))) void*)(&sb[0][0] + e), 16, 0, 0);
    }
  }
  int cur = 0;
  for (int kt = 0; kt < 16; ++kt) {
    __syncthreads();   // buf[cur] staged (vmcnt drained); prior reads of buf[cur^1] ordered
    if (kt + 1 < 16) { // issue next-K stage into the idle buffer — flies through the MFMA phase
      const f16* ta = xhT + ((size_t)(by * 16 + kt + 1) << 13);
      const f16* tb = WqTf + ((size_t)(bx * 16 + kt + 1) << 13);
#pragma unroll
      for (int i = 0; i < 4; ++i) {
        int e = (i * 256 + tid) * 8;
        __builtin_amdgcn_global_load_lds((const __attribute__((address_space(1))) void*)(ta + e),
                                         (__attribute__((address_space(3))) void*)(&sa[cur ^ 1][0] + e), 16, 0, 0);
        __builtin_amdgcn_global_load_lds((const __attribute__((address_space(1))) void*)(tb + e),
                                         (__attribute__((address_space(3))) void*)(&sb[cur ^ 1][0] + e), 16, 0, 0);
      }
    }
#pragma unroll
    for (int ks = 0; ks < 2; ++ks) {
      f16x8 af[2], bf[8];
#pragma unroll
      for (int tr = 0; tr < 2; ++tr)
        af[tr] = *(const f16x8*)(&sa[cur][0] + ((ks * 8 + w * 2 + tr) * 64 + l) * 8);
#pragma unroll
      for (int tc = 0; tc < 8; ++tc)
        bf[tc] = *(const f16x8*)(&sb[cur][0] + ((ks * 8 + tc) * 64 + l) * 8);
#pragma unroll
      for (int tr = 0; tr < 2; ++tr)
#pragma unroll
        for (int tc = 0; tc < 8; ++tc)
          acc[tr][tc] = __builtin_amdgcn_mfma_f32_16x16x32_f16(af[tr], bf[tc], acc[tr][tc], 0, 0, 0);
    }
    cur ^= 1;
  }
  // epilogue scatter
#pragma unroll
  for (int tr = 0; tr < 2; ++tr)
#pragma unroll
    for (int tc = 0; tc < 8; ++tc)
#pragma unroll
      for (int r = 0; r < 4; ++r) {
        int row = by * 128 + w * 32 + tr * 16 + q * 4 + r;
        int col = bx * 128 + tc * 16 + c;
        float v = acc[tr][tc][r];
        int t = col >> 10, head = (col >> 6) & 15, dh = col & 63;
        if (t == 0 || t == 3) v *= 0.125f;
        f16 hv = (f16)v;
        if (t == 4) {
          size_t addr = (size_t)4 * NHSD + (size_t)head * (SEQ * DH) + ((size_t)(row >> 7) << 13)
                      + (size_t)(((((dh >> 5) << 3) + ((row >> 4) & 7)) * 64
                                  + ((((dh >> 3) & 3) << 4) | (row & 15))) * 8 + (dh & 7));
          q6[addr] = hv;
        } else if (t == 5) {
          size_t addr = (size_t)5 * NHSD + (size_t)head * (SEQ * DH) + ((size_t)(row >> 7) << 13)
                      + (size_t)((((((row >> 5) & 3) << 2) + (dh >> 4)) * 64
                                  + ((((row >> 3) & 3) << 4) | (dh & 15))) * 8 + (row & 7));
          q6[addr] = hv;
        } else if (t == 2) {
          q6[(size_t)2 * NHSD + (size_t)(head * SEQ + row) * DH + dh] = hv;
          size_t fa = ((size_t)(row >> 7) << 13)
                    + (size_t)((((((row >> 5) & 3) << 2) + (dh >> 4)) * 64
                                + ((((row >> 3) & 3) << 4) | (dh & 15))) * 8 + (row & 7));
          vuF[(size_t)head * (SEQ * DH) + fa] = hv;
        } else {
          q6[(size_t)t * NHSD + (size_t)(head * SEQ + row) * DH + dh] = hv;
        }
      }
}

// ---------------- tile producer: t1 DIAGONAL tiles only (16/head) + all lk tiles ----------------
__global__ __launch_bounds__(256) void k_t1lk(const f16* __restrict__ q6, f16* __restrict__ t1dT,
                                              f16* __restrict__ lkT) {
  __shared__ f16 st[128 * 128];
  int head = blockIdx.x / 152;
  int p = blockIdx.x % 152;
  bool is_lk = (p >= 16);
  int RB, CB;
  f16* dst;
  if (is_lk) {
    int p2 = p - 16;
    int K = 0, off = 0;
    while (off + (16 - K) <= p2) { off += 16 - K; ++K; }
    RB = K; CB = K + (p2 - off);
    dst = lkT + ((size_t)(head * NTILE + p2) << 14);
  } else {
    RB = p; CB = p;   // diagonal t1 tile
    dst = t1dT + ((size_t)(head * 16 + p) << 14);
  }
  const f16* Ah = q6 + (size_t)(is_lk ? 0 : 3) * NHSD + (size_t)head * SEQ * DH;  // qu_s / qc_s
  const f16* Bh = q6 + (size_t)(is_lk ? 1 : 2) * NHSD + (size_t)head * SEQ * DH;  // ku / vu
  int tid = threadIdx.x, w = tid >> 6, l = tid & 63, q = l >> 4, c = l & 15;
  const f32x4 zf = {0.f, 0.f, 0.f, 0.f};
  f32x4 tacc[2][8];
  for (int tr = 0; tr < 2; ++tr) for (int tc = 0; tc < 8; ++tc) tacc[tr][tc] = zf;
#pragma unroll
  for (int ks = 0; ks < 2; ++ks) {
    f16x8 aq[2], bf[8];
#pragma unroll
    for (int tr = 0; tr < 2; ++tr)
      aq[tr] = *(const f16x8*)(Ah + (size_t)(RB * 128 + w * 32 + tr * 16 + c) * DH + ks * 32 + q * 8);
#pragma unroll
    for (int tc = 0; tc < 8; ++tc)
      bf[tc] = *(const f16x8*)(Bh + (size_t)(CB * 128 + tc * 16 + c) * DH + ks * 32 + q * 8);
#pragma unroll
    for (int tr = 0; tr < 2; ++tr)
#pragma unroll
      for (int tc = 0; tc < 8; ++tc)
        tacc[tr][tc] = __builtin_amdgcn_mfma_f32_16x16x32_f16(aq[tr], bf[tc], tacc[tr][tc], 0, 0, 0);
  }
#pragma unroll
  for (int tr = 0; tr < 2; ++tr)
#pragma unroll
    for (int tc = 0; tc < 8; ++tc)
#pragma unroll
      for (int r = 0; r < 4; ++r) {
        int row = w * 32 + tr * 16 + q * 4 + r;
        int col = tc * 16 + c;
        int rg = RB * 128 + row, cg = CB * 128 + col;
        float v = tacc[tr][tc][r];
        f16 ov;
        if (is_lk) ov = (cg > rg) ? (f16)__builtin_amdgcn_rcpf(1.f + __expf(-v)) : (f16)(0.f);
        else       ov = (cg <= rg) ? (f16)v : (f16)(0.f);
        st[(row << 7) + (((col >> 3) ^ (row & 15)) << 3) + (col & 7)] = ov;
      }
  __syncthreads();
#pragma unroll
  for (int i = 0; i < 8; ++i) {
    int ch = i * 256 + tid;
    int ks = ch >> 9, rb = (ch >> 6) & 7, ln = ch & 63;
    int qq = ln >> 4, cc = ln & 15;
    int row = rb * 16 + cc, cchunk = ks * 4 + qq;
    f16x8 v = *(const f16x8*)(st + (row << 7) + ((cchunk ^ (row & 15)) << 3));
    *(f16x8*)(dst + (size_t)ch * 8) = v;
  }
}

// ---------------- prefix kernel: PP(K,J) = sum_{J'=K..J} lkT(K,J') @ vu(J') ----------------
__global__ __launch_bounds__(256) void k_prefix(const f16* __restrict__ lkT, const f16* __restrict__ vuF,
                                                f16* __restrict__ PPT) {
  __shared__ f16 lkb[2][16384];
  __shared__ f16 vub[2][8192];
  __shared__ f16 st[8192];
  int head = blockIdx.x >> 4, K = blockIdx.x & 15;
  int offK = 16 * K - (K * (K - 1)) / 2;
  const f16* lkh = lkT + ((size_t)(head * NTILE) << 14);
  const f16* vuh = vuF + (size_t)head * (SEQ * DH);
  f16* pph = PPT + ((size_t)(head * NTILE) << 13);
  int tid = threadIdx.x, w = tid >> 6, l = tid & 63, q = l >> 4, c = l & 15;
  f32x4 acc[2][4];
  const f32x4 zf = {0.f, 0.f, 0.f, 0.f};
  for (int tr = 0; tr < 2; ++tr) for (int tv = 0; tv < 4; ++tv) acc[tr][tv] = zf;
  // prologue: stage J=K into buf 0
  {
    const f16* lt = lkh + ((size_t)offK << 14);
#pragma unroll
    for (int i = 0; i < 8; ++i) {
      int e = (i * 256 + tid) * 8;
      __builtin_amdgcn_global_load_lds((const __attribute__((address_space(1))) void*)(lt + e),
                                       (__attribute__((address_space(3))) void*)(&lkb[0][0] + e), 16, 0, 0);
    }
    const f16* vt_ = vuh + ((size_t)K << 13);
#pragma unroll
    for (int i = 0; i < 4; ++i) {
      int e = (i * 256 + tid) * 8;
      __builtin_amdgcn_global_load_lds((const __attribute__((address_space(1))) void*)(vt_ + e),
                                       (__attribute__((address_space(3))) void*)(&vub[0][0] + e), 16, 0, 0);
    }
  }
  int pb = 0;
  for (int J = K; J < 16; ++J) {
    __syncthreads();   // buf[pb] staged; previous st re-reads complete
    if (J < 15) {      // prefetch next J into the idle buffer (overlaps MFMA + st phases)
      const f16* lt = lkh + ((size_t)(offK + (J + 1 - K)) << 14);
#pragma unroll
      for (int i = 0; i < 8; ++i) {
        int e = (i * 256 + tid) * 8;
        __builtin_amdgcn_global_load_lds((const __attribute__((address_space(1))) void*)(lt + e),
                                         (__attribute__((address_space(3))) void*)(&lkb[pb ^ 1][0] + e), 16, 0, 0);
      }
      const f16* vt_ = vuh + ((size_t)(J + 1) << 13);
#pragma unroll
      for (int i = 0; i < 4; ++i) {
        int e = (i * 256 + tid) * 8;
        __builtin_amdgcn_global_load_lds((const __attribute__((address_space(1))) void*)(vt_ + e),
                                         (__attribute__((address_space(3))) void*)(&vub[pb ^ 1][0] + e), 16, 0, 0);
      }
    }
#pragma unroll
    for (int ks = 0; ks < 4; ++ks) {
      f16x8 af[2], bf[4];
#pragma unroll
      for (int tr = 0; tr < 2; ++tr)
        af[tr] = *(const f16x8*)(&lkb[pb][0] + ((ks * 8 + w * 2 + tr) * 64 + l) * 8);
#pragma unroll
      for (int tv = 0; tv < 4; ++tv)
        bf[tv] = *(const f16x8*)(&vub[pb][0] + ((ks * 4 + tv) * 64 + l) * 8);
#pragma unroll
      for (int tr = 0; tr < 2; ++tr)
#pragma unroll
        for (int tv = 0; tv < 4; ++tv)
          acc[tr][tv] = __builtin_amdgcn_mfma_f32_16x16x32_f16(af[tr], bf[tv], acc[tr][tv], 0, 0, 0);
    }
    // acc -> st (f16, swizzled 128x64)
#pragma unroll
    for (int tr = 0; tr < 2; ++tr)
#pragma unroll
      for (int tv = 0; tv < 4; ++tv)
#pragma unroll
        for (int r = 0; r < 4; ++r) {
          int row = w * 32 + tr * 16 + q * 4 + r;
          int col = tv * 16 + c;
          st[(row << 6) + (((col >> 3) ^ (row & 7)) << 3) + (col & 7)] = (f16)acc[tr][tv][r];
        }
    __syncthreads();   // st complete (prefetch had the MFMA phase to fly)
    // st re-read in frag order -> PPT(K,J)
    f16* dst = pph + ((size_t)(offK + (J - K)) << 13);
#pragma unroll
    for (int i = 0; i < 4; ++i) {
      int slot = i * 256 + tid;
      int chunk = slot >> 6, ln = slot & 63;
      int ks2 = chunk >> 3, tc = chunk & 7, qq = ln >> 4, cc = ln & 15;
      int row = tc * 16 + cc, cch = ks2 * 4 + qq;
      f16x8 v = *(const f16x8*)(st + (row << 6) + ((cch ^ (row & 7)) << 3));
      *(f16x8*)(dst + (size_t)slot * 8) = v;
    }
    pb ^= 1;
  }
}

// ---------------- flash (R25 structure, unchanged): R24 pipeline + 8 waves x 16 rows ----------------
__global__ __launch_bounds__(512, 1) void k_flash(const f16* __restrict__ q6, const f16* __restrict__ t1dT,
                                                  const f16* __restrict__ lkT, const f16* __restrict__ PPT,
                                                  f16* __restrict__ pO, float* __restrict__ pML) {
  __shared__ f16 Sb[2][40960];      // 2 x 80KB: each = lk(0) | pp(16384) | kc(24576) | vt(32768)
  int bid = blockIdx.x;
  int big = bid & 1;
  int rest = bid >> 1;
  int head = ((rest & 7) << 1) | ((rest >> 3) & 1);
  int r2 = 31 - (rest >> 4);        // reversed: big pairs dispatch first
  int a = 0, s = 0;
  {
    int acc = 0;
    for (int aa = 0; aa < 8; ++aa) {
      int si = ns2(aa);
      if (r2 >= acc && r2 < acc + si) { a = aa; s = r2 - acc; }
      acc += si;
    }
  }
  int I1 = 2 * a + 1;
  int S_ = ns2(a);
  int Ktot = I1 + 1;
  int K0 = (Ktot * s) / S_, K1 = (Ktot * (s + 1)) / S_;
  int IB = 2 * a + big;             // this block's I-tile
  int Kbeg = (K0 < IB + 1) ? K0 : IB + 1;
  int Kend = (K1 < IB + 1) ? K1 : IB + 1;

  const f16* qc  = q6 + (size_t)3 * NHSD + (size_t)head * SEQ * DH;   // pre-scaled
  const f16* kcF = q6 + (size_t)4 * NHSD + (size_t)head * (SEQ * DH);
  const f16* vtF = q6 + (size_t)5 * NHSD + (size_t)head * (SEQ * DH);
  int tid = threadIdx.x, w = tid >> 6, l = tid & 63, q = l >> 4, c = l & 15;
  const f16* lkh = lkT + ((size_t)(head * NTILE) << 14);
  const f16* pph = PPT + ((size_t)(head * NTILE) << 13);
  const f16* t1d = t1dT + ((size_t)(head * 16 + IB) << 14);

  // per-wave constants in registers (wave w owns rows [w*16, w*16+16))
  f16x8 a_qc[2];
#pragma unroll
  for (int ks = 0; ks < 2; ++ks)
    a_qc[ks] = *(const f16x8*)(qc + (size_t)(IB * 128 + w * 16 + c) * DH + ks * 32 + q * 8);
  f16x8 a_t1[4];
#pragma unroll
  for (int ks = 0; ks < 4; ++ks)
    a_t1[ks] = *(const f16x8*)(t1d + (size_t)((ks * 8 + w) * 64 + l) * 8);

  f32x4 su[8], oacc[4];
  float m_i[4], l_i[4];
  const f32x4 zf = {0.f, 0.f, 0.f, 0.f};
  for (int tv = 0; tv < 4; ++tv) oacc[tv] = zf;
  for (int r = 0; r < 4; ++r) { m_i[r] = -INFINITY; l_i[r] = 0.f; }

  // prologue: stage K=Kbeg into buf 0
  if (Kbeg < Kend) {
    int K = Kbeg;
    int offK = 16 * K - (K * (K - 1)) / 2;
    f16* D = &Sb[0][0];
    const f16* p1 = lkh + ((size_t)(offK + (IB - K)) << 14);
#pragma unroll
    for (int i = 0; i < 4; ++i) {
      int e = (i * 512 + tid) * 8;
      __builtin_amdgcn_global_load_lds((const __attribute__((address_space(1))) void*)(p1 + e),
                                       (__attribute__((address_space(3))) void*)(D + e), 16, 0, 0);
    }
    if (K < IB) {
      const f16* pp = pph + ((size_t)(offK + (IB - 1 - K)) << 13);
#pragma unroll
      for (int i = 0; i < 2; ++i) {
        int e = (i * 512 + tid) * 8;
        __builtin_amdgcn_global_load_lds((const __attribute__((address_space(1))) void*)(pp + e),
                                         (__attribute__((address_space(3))) void*)(D + 16384 + e), 16, 0, 0);
      }
    }
    const f16* kt_ = kcF + ((size_t)K << 13);
    const f16* vv_ = vtF + ((size_t)K << 13);
#pragma unroll
    for (int i = 0; i < 2; ++i) {
      int e = (i * 512 + tid) * 8;
      __builtin_amdgcn_global_load_lds((const __attribute__((address_space(1))) void*)(kt_ + e),
                                       (__attribute__((address_space(3))) void*)(D + 24576 + e), 16, 0, 0);
      __builtin_amdgcn_global_load_lds((const __attribute__((address_space(1))) void*)(vv_ + e),
                                       (__attribute__((address_space(3))) void*)(D + 32768 + e), 16, 0, 0);
    }
  }

  int cur = 0;
  for (int K = Kbeg; K < Kend; ++K) {
#pragma unroll
    for (int tc = 0; tc < 8; ++tc) su[tc] = zf;

    __syncthreads();   // top: buf[cur]'s stage drained; prior PV reads of buf[cur^1] ordered

    // issue next-K stage into buf[cur^1] — flies through the entire compute phase
    if (K + 1 < Kend) {
      int Kn = K + 1;
      int offKn = 16 * Kn - (Kn * (Kn - 1)) / 2;
      f16* D = &Sb[cur ^ 1][0];
      const f16* p1 = lkh + ((size_t)(offKn + (IB - Kn)) << 14);
#pragma unroll
      for (int i = 0; i < 4; ++i) {
        int e = (i * 512 + tid) * 8;
        __builtin_amdgcn_global_load_lds((const __attribute__((address_space(1))) void*)(p1 + e),
                                         (__attribute__((address_space(3))) void*)(D + e), 16, 0, 0);
      }
      if (Kn < IB) {
        const f16* pp = pph + ((size_t)(offKn + (IB - 1 - Kn)) << 13);
#pragma unroll
        for (int i = 0; i < 2; ++i) {
          int e = (i * 512 + tid) * 8;
          __builtin_amdgcn_global_load_lds((const __attribute__((address_space(1))) void*)(pp + e),
                                           (__attribute__((address_space(3))) void*)(D + 16384 + e), 16, 0, 0);
        }
      }
      const f16* kt_ = kcF + ((size_t)Kn << 13);
      const f16* vv_ = vtF + ((size_t)Kn << 13);
#pragma unroll
      for (int i = 0; i < 2; ++i) {
        int e = (i * 512 + tid) * 8;
        __builtin_amdgcn_global_load_lds((const __attribute__((address_space(1))) void*)(kt_ + e),
                                         (__attribute__((address_space(3))) void*)(D + 24576 + e), 16, 0, 0);
        __builtin_amdgcn_global_load_lds((const __attribute__((address_space(1))) void*)(vv_ + e),
                                         (__attribute__((address_space(3))) void*)(D + 32768 + e), 16, 0, 0);
      }
    }

    f16* bufc = &Sb[cur][0];
    // PP term: su += a_qc @ PP(K, IB-1)
    if (K < IB) {
      const f16* ppb = bufc + 16384;
#pragma unroll
      for (int ks = 0; ks < 2; ++ks) {
        f16x8 bf[8];
#pragma unroll
        for (int tc = 0; tc < 8; ++tc)
          bf[tc] = *(const f16x8*)(ppb + ((ks * 8 + tc) * 64 + l) * 8);
#pragma unroll
        for (int tc = 0; tc < 8; ++tc)
          su[tc] = __builtin_amdgcn_mfma_f32_16x16x32_f16(a_qc[ks], bf[tc], su[tc], 0, 0, 0);
      }
    }
    // t1d term: su += a_t1 @ lk(K, IB)^T
    {
      __builtin_amdgcn_s_setprio(1);
#pragma unroll
      for (int ks = 0; ks < 4; ++ks) {
        f16x8 bf[8];
#pragma unroll
        for (int tc = 0; tc < 8; ++tc)
          bf[tc] = *(const f16x8*)(bufc + ((ks * 8 + tc) * 64 + l) * 8);
#pragma unroll
        for (int tc = 0; tc < 8; ++tc)
          su[tc] = __builtin_amdgcn_mfma_f32_16x16x32_f16(a_t1[ks], bf[tc], su[tc], 0, 0, 0);
      }
      __builtin_amdgcn_s_setprio(0);
    }
    // scores = Sc - silu(Su)
#pragma unroll
    for (int tc = 0; tc < 8; ++tc)
#pragma unroll
      for (int r = 0; r < 4; ++r) {
        float v = su[tc][r];
        su[tc][r] = -v * __builtin_amdgcn_rcpf(1.f + __expf(-v));
      }
    {
      const f16* skc = bufc + 24576;
#pragma unroll
      for (int ks = 0; ks < 2; ++ks) {
        f16x8 bk[8];
#pragma unroll
        for (int tc = 0; tc < 8; ++tc)
          bk[tc] = *(const f16x8*)(skc + ((ks * 8 + tc) * 64 + l) * 8);
#pragma unroll
        for (int tc = 0; tc < 8; ++tc)
          su[tc] = __builtin_amdgcn_mfma_f32_16x16x32_f16(a_qc[ks], bk[tc], su[tc], 0, 0, 0);
      }
    }
    if (K == IB) {     // strict causal mask on the diagonal block
#pragma unroll
      for (int tc = 0; tc < 8; ++tc)
#pragma unroll
        for (int r = 0; r < 4; ++r) {
          int rg = w * 16 + q * 4 + r;
          int cg = tc * 16 + c;
          if (cg > rg) su[tc][r] = -INFINITY;
        }
    }
    // online softmax
#pragma unroll
    for (int r = 0; r < 4; ++r) {
      float mx = su[0][r];
#pragma unroll
      for (int tc = 1; tc < 8; ++tc) mx = fmaxf(mx, su[tc][r]);
      mx = fmaxf(mx, __shfl_xor(mx, 1)); mx = fmaxf(mx, __shfl_xor(mx, 2));
      mx = fmaxf(mx, __shfl_xor(mx, 4)); mx = fmaxf(mx, __shfl_xor(mx, 8));
      float mnew  = fmaxf(m_i[r], mx);
      float alpha = __expf(m_i[r] - mnew);
      float ssum = 0.f;
#pragma unroll
      for (int tc = 0; tc < 8; ++tc) {
        float pp = __expf(su[tc][r] - mnew);
        su[tc][r] = pp;
        ssum += pp;
      }
      ssum += __shfl_xor(ssum, 1); ssum += __shfl_xor(ssum, 2);
      ssum += __shfl_xor(ssum, 4); ssum += __shfl_xor(ssum, 8);
      l_i[r] = l_i[r] * alpha + ssum;
      m_i[r] = mnew;
#pragma unroll
      for (int tv = 0; tv < 4; ++tv) oacc[tv][r] *= alpha;
    }
    // join barrier: lgkmcnt-only (keeps next-K stage in flight).
    asm volatile("s_waitcnt lgkmcnt(0)" ::: "memory");
    __builtin_amdgcn_sched_barrier(0);
    __builtin_amdgcn_s_barrier();
    __builtin_amdgcn_sched_barrier(0);
    // P -> Pb (= bufc lk region; own 16-row region of the 128-row buffer)
#pragma unroll
    for (int tc = 0; tc < 8; ++tc)
#pragma unroll
      for (int r = 0; r < 4; ++r) {
        int row = w * 16 + q * 4 + r;    // 0..127
        int col = tc * 16 + c;
        bufc[(row << 7) + (((col >> 3) ^ (row & 15)) << 3) + (col & 7)] = (f16)su[tc][r];
      }
    // PV: A = P (own rows), B = staged vt
    {
      const f16* svt = bufc + 32768;
#pragma unroll
      for (int ks = 0; ks < 4; ++ks) {
        int ck = ks * 4 + q;
        f16x8 ap, bv[4];
        ap = *(const f16x8*)(bufc + ((w * 16 + c) << 7) + ((ck ^ c) << 3));
#pragma unroll
        for (int tv = 0; tv < 4; ++tv)
          bv[tv] = *(const f16x8*)(svt + ((ks * 4 + tv) * 64 + l) * 8);
#pragma unroll
        for (int tv = 0; tv < 4; ++tv)
          oacc[tv] = __builtin_amdgcn_mfma_f32_16x16x32_f16(ap, bv[tv], oacc[tv], 0, 0, 0);
      }
    }
    cur ^= 1;
  }

  // ---- unnormalized partial: slot = head*64 + prefix(IB) + s (empty ranges write m=-inf) ----
  int slot = head * SLOTS_PER_HEAD + slot_base(IB) + s;
  f16* po = pO + (size_t)slot * (128 * 64);
  float* pml = pML + (size_t)slot * 256;
  if (c == 0) {
#pragma unroll
    for (int r = 0; r < 4; ++r) {
      int row = w * 16 + q * 4 + r;
      pml[row] = m_i[r];
      pml[128 + row] = l_i[r];
    }
  }
#pragma unroll
  for (int tv = 0; tv < 4; ++tv)
#pragma unroll
    for (int r = 0; r < 4; ++r) {
      int row = w * 16 + q * 4 + r;
      int col = tv * 16 + c;
      po[row * 64 + col] = (f16)oacc[tv][r];
    }
}

// ---------------- merge partials -> oh [2048][1024] f16 ----------------
__global__ __launch_bounds__(256) void k_merge(const f16* __restrict__ pO, const float* __restrict__ pML,
                                               f16* __restrict__ oh) {
  int head = blockIdx.x >> 4, I = blockIdx.x & 15;
  int S_ = ns2(I >> 1);
  int tid = threadIdx.x;
  int row = tid >> 1, half = tid & 1;
  int base = head * SLOTS_PER_HEAD + slot_base(I);
  float m[MAXS], lv[MAXS];
  float mstar = -INFINITY;
#pragma unroll
  for (int s = 0; s < MAXS; ++s)
    if (s < S_) {
      m[s] = pML[(size_t)(base + s) * 256 + row];
      lv[s] = pML[(size_t)(base + s) * 256 + 128 + row];
      mstar = fmaxf(mstar, m[s]);
    }
  float wt[MAXS];
  float lsum = 0.f;
#pragma unroll
  for (int s = 0; s < MAXS; ++s)
    if (s < S_) {
      wt[s] = __expf(m[s] - mstar);   // empty partials (m=-inf) get weight 0
      lsum += lv[s] * wt[s];
    }
  float rinv = __builtin_amdgcn_rcpf(lsum);
#pragma unroll
  for (int cc = 0; cc < 32; cc += 8) {
    float acc[8] = {0.f, 0.f, 0.f, 0.f, 0.f, 0.f, 0.f, 0.f};
#pragma unroll
    for (int s = 0; s < MAXS; ++s)
      if (s < S_) {
        f16x8 v = *(const f16x8*)(pO + (size_t)(base + s) * 8192 + row * 64 + half * 32 + cc);
#pragma unroll
        for (int e = 0; e < 8; ++e) acc[e] += wt[s] * (float)v[e];
      }
    f16x8 o;
#pragma unroll
    for (int e = 0; e < 8; ++e) o[e] = (f16)(acc[e] * rinv);
    *(f16x8*)(oh + (size_t)(I * 128 + row) * DIM + head * 64 + half * 32 + cc) = o;
  }
}

// ---------------- final GEMM: 128x64 tiles, grid (16,16) -> 256 blocks ----------------
__global__ __launch_bounds__(256) void k_gemm_out(const f16* __restrict__ A, const f16* __restrict__ B,
                                                  float* __restrict__ out) {
  __shared__ f16 sa[128 * 72];
  __shared__ f16 sb[64 * 72];
  int bx = blockIdx.x, by = blockIdx.y;
  int tid = threadIdx.x, w = tid >> 6, l = tid & 63, q = l >> 4, c = l & 15;
  f32x4 acc[2][4];
  const f32x4 zf = {0.f, 0.f, 0.f, 0.f};
  for (int i = 0; i < 2; ++i) for (int j = 0; j < 4; ++j) acc[i][j] = zf;
  for (int kt = 0; kt < DIM / 64; ++kt) {
    __syncthreads();
#pragma unroll
    for (int it = 0; it < 4; ++it) {
      int idx = it * 256 + tid; int r = idx >> 3, ch = idx & 7;
      *(float4*)(sa + r * 72 + ch * 8) = *(const float4*)(A + (size_t)(by * 128 + r) * DIM + kt * 64 + ch * 8);
    }
#pragma unroll
    for (int it = 0; it < 2; ++it) {
      int idx = it * 256 + tid; int r = idx >> 3, ch = idx & 7;
      *(float4*)(sb + r * 72 + ch * 8) = *(const float4*)(B + (size_t)(bx * 64 + r) * DIM + kt * 64 + ch * 8);
    }
    __syncthreads();
#pragma unroll
    for (int ks = 0; ks < 2; ++ks) {
      f16x8 af[2], bf[4];
#pragma unroll
      for (int tr = 0; tr < 2; ++tr) af[tr] = *(const f16x8*)(sa + (w * 32 + tr * 16 + c) * 72 + ks * 32 + q * 8);
#pragma unroll
      for (int tc = 0; tc < 4; ++tc) bf[tc] = *(const f16x8*)(sb + (tc * 16 + c) * 72 + ks * 32 + q * 8);
#pragma unroll
      for (int tr = 0; tr < 2; ++tr)
#pragma unroll
        for (int tc = 0; tc < 4; ++tc)
          acc[tr][tc] = __builtin_amdgcn_mfma_f32_16x16x32_f16(af[tr], bf[tc], acc[tr][tc], 0, 0, 0);
    }
  }
#pragma unroll
  for (int tr = 0; tr < 2; ++tr)
#pragma unroll
    for (int tc = 0; tc < 4; ++tc)
#pragma unroll
      for (int r = 0; r < 4; ++r) {
        int row = by * 128 + w * 32 + tr * 16 + q * 4 + r;
        int col = bx * 64 + tc * 16 + c;
        out[(size_t)row * DIM + col] = acc[tr][tc][r];
      }
}

extern "C" void kernel_launch(void* const* d_in, const int* in_sizes, int n_in,
                              void* d_out, int out_size, void* d_ws, size_t ws_size,
                              hipStream_t stream) {
  const float* x  = (const float*)d_in[0];
  const float* Wq = (const float*)d_in[1];
  const float* Wo = (const float*)d_in[2];
  float* out = (float*)d_out;

  f16* ws = (f16*)d_ws;
  size_t off = 0;
  f16* q6   = ws + off; off += (size_t)6 * NHSD;                        // 25.2 MB
  f16* vuF  = ws + off; off += (size_t)NHSD;                            // 4.2 MB (vu^T frag tiles)
  f16* xhT  = ws + off; off += (size_t)SEQ * DIM;                       // 4.2 MB
  f16* WqTf = ws + off; off += (size_t)NCOLS * DIM;                     // 12.6 MB
  f16* WoT  = ws + off; off += (size_t)DIM * DIM;                       // 2.1 MB
  f16* oh   = ws + off; off += (size_t)SEQ * DIM;                       // 4.2 MB
  f16* pO   = ws + off; off += (size_t)NH * SLOTS_PER_HEAD * 128 * 64;  // 16.8 MB
  f16* lkT  = ws + off; off += (size_t)NH * NTILE * 128 * 128;          // 71.3 MB
  f16* t1dT = ws + off; off += (size_t)NH * 16 * 128 * 128;             // 8.4 MB (diag t1 only)
  f16* PPT  = ws + off; off += (size_t)NH * NTILE * 128 * 64;           // 35.7 MB (prefix tiles)
  float* pML = (float*)(ws + off); off += (size_t)NH * SLOTS_PER_HEAD * 256 * 2; // 1.05 MB
  // total ~186 MB of workspace

  k_prep<<<1280, 256, 0, stream>>>(x, xhT, Wq, WqTf, Wo, WoT);
  k_gemm_qkv<<<dim3(NCOLS / 128, SEQ / 128), 256, 0, stream>>>(xhT, WqTf, q6, vuF);
  k_t1lk<<<NH * 152, 256, 0, stream>>>(q6, t1dT, lkT);
  k_prefix<<<NH * 16, 256, 0, stream>>>(lkT, vuF, PPT);
  k_flash<<<NH * 64, 512, 0, stream>>>(q6, t1dT, lkT, PPT, pO, pML);
  k_merge<<<NH * 16, 256, 0, stream>>>(pO, pML, oh);
  k_gemm_out<<<dim3(DIM / 64, SEQ / 128), 256, 0, stream>>>(oh, WoT, out);
}

// Round 14
// 323.151 us; speedup vs baseline: 1.0441x; 1.0255x over previous
//
#include <hip/hip_runtime.h>
#include <math.h>

typedef _Float16 f16;
typedef _Float16 f16x4 __attribute__((ext_vector_type(4)));
typedef _Float16 f16x8 __attribute__((ext_vector_type(8)));
typedef float f32x4 __attribute__((ext_vector_type(4)));

#define SEQ   2048
#define DIM   1024
#define NH    16
#define DH    64
#define NCOLS 6144
#define NHSD  (NH*SEQ*DH)   /* 2,097,152 elements per qkv sub-tensor */
#define NTILE 136           /* lk tiles per head (triangular) */
#define MAXS  9
#define SLOTS_PER_HEAD 64   /* sum over I of NS2[I>>1] */

// pair-splits: pair a = (I0=2a, I1=2a+1); NS2 K-splits per pair.
__device__ __forceinline__ int ns2(int a) {
  const int NS2[8] = {1,1,2,3,4,5,7,9};
  return NS2[a];
}
__device__ __forceinline__ int slot_base(int I) {  // prefix of NS2[I'>>1] over I' < I
  const int PF[16] = {0,1,2,3,4,6,8,11,14,18,22,27,32,39,46,55};
  return PF[I];
}

// ------------- transpose + cast: out[c][r] = (f16) in[r][c], in is R x C (Wo only) -------------
__global__ __launch_bounds__(256) void k_tcast(const float* __restrict__ in, f16* __restrict__ out,
                                               int R, int C) {
  __shared__ f16 t[64 * 66];
  int bc = blockIdx.x, br = blockIdx.y;
  for (int it = 0; it < 16; ++it) {
    int idx = it * 256 + threadIdx.x;
    int r = idx >> 6, c = idx & 63;
    t[r * 66 + c] = (f16)in[(size_t)(br * 64 + r) * C + bc * 64 + c];
  }
  __syncthreads();
  for (int it = 0; it < 16; ++it) {
    int idx = it * 256 + threadIdx.x;
    int oc = idx >> 6, orr = idx & 63;
    out[(size_t)(bc * 64 + oc) * R + br * 64 + orr] = t[orr * 66 + oc];
  }
}

// ---- prepA: cast x (f32) into A-frag-chunk tiles ----
__global__ __launch_bounds__(256) void k_prepA(const float* __restrict__ x, f16* __restrict__ xhT) {
  int kt = blockIdx.x, by = blockIdx.y;
  f16* dst = xhT + ((size_t)(by * 16 + kt) << 13);
  int tid = threadIdx.x;
#pragma unroll
  for (int i = 0; i < 4; ++i) {
    int idx = i * 256 + tid;
    int chunk = idx >> 6, lane = idx & 63;
    int rb = chunk & 7, ks = chunk >> 3;
    int row = by * 128 + rb * 16 + (lane & 15);
    int kk = kt * 64 + ks * 32 + ((lane >> 4) << 3);
    const float* p = x + (size_t)row * DIM + kk;
    float4 lo = *(const float4*)p, hi = *(const float4*)(p + 4);
    f16x8 h;
    h[0] = (f16)lo.x; h[1] = (f16)lo.y; h[2] = (f16)lo.z; h[3] = (f16)lo.w;
    h[4] = (f16)hi.x; h[5] = (f16)hi.y; h[6] = (f16)hi.z; h[7] = (f16)hi.w;
    *(f16x8*)(dst + (size_t)idx * 8) = h;
  }
}

// ---- prepB (R26 LDS-transpose version, standalone): Wq[k][n] -> B-frag-chunk tiles.
// 64x128 f32 tile loads fully coalesced (512B rows), f16 cast into LDS (stride 130 breaks
// transposed-read bank collisions), frags emitted from LDS. ----
__global__ __launch_bounds__(256) void k_prepB(const float* __restrict__ Wq, f16* __restrict__ WqTf) {
  __shared__ f16 sw[64 * 130];
  int kt = blockIdx.x, bx = blockIdx.y;
  int tid = threadIdx.x;
#pragma unroll
  for (int it = 0; it < 8; ++it) {
    int idx = it * 256 + tid;          // 0..2047
    int r = idx >> 5, c4 = idx & 31;   // row, float4-chunk
    float4 v = *(const float4*)(Wq + (size_t)(kt * 64 + r) * NCOLS + bx * 128 + c4 * 4);
    f16* d = sw + r * 130 + c4 * 4;
    d[0] = (f16)v.x; d[1] = (f16)v.y; d[2] = (f16)v.z; d[3] = (f16)v.w;
  }
  __syncthreads();
  f16* dst = WqTf + ((size_t)(bx * 16 + kt) << 13);
#pragma unroll
  for (int i = 0; i < 4; ++i) {
    int idx = i * 256 + tid;
    int chunk = idx >> 6, lane = idx & 63;
    int rb = chunk & 7, ks = chunk >> 3;
    int nl = rb * 16 + (lane & 15);
    int kl = ks * 32 + ((lane >> 4) << 3);
    f16x8 h;
#pragma unroll
    for (int j = 0; j < 8; ++j) h[j] = sw[(kl + j) * 130 + nl];
    *(f16x8*)(dst + (size_t)idx * 8) = h;
  }
}

// ---------------- qkv GEMM (R27: double-buffered K-pipeline, one barrier per step) ----------------
__global__ __launch_bounds__(256) void k_gemm_qkv(const f16* __restrict__ xhT, const f16* __restrict__ WqTf,
                                                  f16* __restrict__ q6, f16* __restrict__ vuF) {
  __shared__ f16 sa[2][8192];
  __shared__ f16 sb[2][8192];
  int bx = blockIdx.x, by = blockIdx.y;
  int tid = threadIdx.x, w = tid >> 6, l = tid & 63, q = l >> 4, c = l & 15;
  f32x4 acc[2][8];
  const f32x4 zf = {0.f, 0.f, 0.f, 0.f};
  for (int i = 0; i < 2; ++i) for (int j = 0; j < 8; ++j) acc[i][j] = zf;

  // prologue: stage kt=0 into buf 0
  {
    const f16* ta = xhT + ((size_t)(by * 16) << 13);
    const f16* tb = WqTf + ((size_t)(bx * 16) << 13);
#pragma unroll
    for (int i = 0; i < 4; ++i) {
      int e = (i * 256 + tid) * 8;
      __builtin_amdgcn_global_load_lds((const __attribute__((address_space(1))) void*)(ta + e),
                                       (__attribute__((address_space(3))) void*)(&sa[0][0] + e), 16, 0, 0);
      __builtin_amdgcn_global_load_lds((const __attribute__((address_space(1))) void*)(tb + e),
                                       (__attribute__((address_space(3))) void*)(&sb[0][0] + e), 16, 0, 0);
    }
  }
  int cur = 0;
  for (int kt = 0; kt < 16; ++kt) {
    __syncthreads();   // buf[cur] staged (vmcnt drained); prior reads of buf[cur^1] ordered
    if (kt + 1 < 16) { // issue next-K stage into the idle buffer — flies through the MFMA phase
      const f16* ta = xhT + ((size_t)(by * 16 + kt + 1) << 13);
      const f16* tb = WqTf + ((size_t)(bx * 16 + kt + 1) << 13);
#pragma unroll
      for (int i = 0; i < 4; ++i) {
        int e = (i * 256 + tid) * 8;
        __builtin_amdgcn_global_load_lds((const __attribute__((address_space(1))) void*)(ta + e),
                                         (__attribute__((address_space(3))) void*)(&sa[cur ^ 1][0] + e), 16, 0, 0);
        __builtin_amdgcn_global_load_lds((const __attribute__((address_space(1))) void*)(tb + e),
                                         (__attribute__((address_space(3))) void*)(&sb[cur ^ 1][0] + e), 16, 0, 0);
      }
    }
#pragma unroll
    for (int ks = 0; ks < 2; ++ks) {
      f16x8 af[2], bf[8];
#pragma unroll
      for (int tr = 0; tr < 2; ++tr)
        af[tr] = *(const f16x8*)(&sa[cur][0] + ((ks * 8 + w * 2 + tr) * 64 + l) * 8);
#pragma unroll
      for (int tc = 0; tc < 8; ++tc)
        bf[tc] = *(const f16x8*)(&sb[cur][0] + ((ks * 8 + tc) * 64 + l) * 8);
#pragma unroll
      for (int tr = 0; tr < 2; ++tr)
#pragma unroll
        for (int tc = 0; tc < 8; ++tc)
          acc[tr][tc] = __builtin_amdgcn_mfma_f32_16x16x32_f16(af[tr], bf[tc], acc[tr][tc], 0, 0, 0);
    }
    cur ^= 1;
  }
  // epilogue scatter
#pragma unroll
  for (int tr = 0; tr < 2; ++tr)
#pragma unroll
    for (int tc = 0; tc < 8; ++tc)
#pragma unroll
      for (int r = 0; r < 4; ++r) {
        int row = by * 128 + w * 32 + tr * 16 + q * 4 + r;
        int col = bx * 128 + tc * 16 + c;
        float v = acc[tr][tc][r];
        int t = col >> 10, head = (col >> 6) & 15, dh = col & 63;
        if (t == 0 || t == 3) v *= 0.125f;
        f16 hv = (f16)v;
        if (t == 4) {
          size_t addr = (size_t)4 * NHSD + (size_t)head * (SEQ * DH) + ((size_t)(row >> 7) << 13)
                      + (size_t)(((((dh >> 5) << 3) + ((row >> 4) & 7)) * 64
                                  + ((((dh >> 3) & 3) << 4) | (row & 15))) * 8 + (dh & 7));
          q6[addr] = hv;
        } else if (t == 5) {
          size_t addr = (size_t)5 * NHSD + (size_t)head * (SEQ * DH) + ((size_t)(row >> 7) << 13)
                      + (size_t)((((((row >> 5) & 3) << 2) + (dh >> 4)) * 64
                                  + ((((row >> 3) & 3) << 4) | (dh & 15))) * 8 + (row & 7));
          q6[addr] = hv;
        } else if (t == 2) {
          q6[(size_t)2 * NHSD + (size_t)(head * SEQ + row) * DH + dh] = hv;
          size_t fa = ((size_t)(row >> 7) << 13)
                    + (size_t)((((((row >> 5) & 3) << 2) + (dh >> 4)) * 64
                                + ((((row >> 3) & 3) << 4) | (dh & 15))) * 8 + (row & 7));
          vuF[(size_t)head * (SEQ * DH) + fa] = hv;
        } else {
          q6[(size_t)t * NHSD + (size_t)(head * SEQ + row) * DH + dh] = hv;
        }
      }
}

// ---------------- tile producer: t1 DIAGONAL tiles only (16/head) + all lk tiles ----------------
__global__ __launch_bounds__(256) void k_t1lk(const f16* __restrict__ q6, f16* __restrict__ t1dT,
                                              f16* __restrict__ lkT) {
  __shared__ f16 st[128 * 128];
  int head = blockIdx.x / 152;
  int p = blockIdx.x % 152;
  bool is_lk = (p >= 16);
  int RB, CB;
  f16* dst;
  if (is_lk) {
    int p2 = p - 16;
    int K = 0, off = 0;
    while (off + (16 - K) <= p2) { off += 16 - K; ++K; }
    RB = K; CB = K + (p2 - off);
    dst = lkT + ((size_t)(head * NTILE + p2) << 14);
  } else {
    RB = p; CB = p;   // diagonal t1 tile
    dst = t1dT + ((size_t)(head * 16 + p) << 14);
  }
  const f16* Ah = q6 + (size_t)(is_lk ? 0 : 3) * NHSD + (size_t)head * SEQ * DH;  // qu_s / qc_s
  const f16* Bh = q6 + (size_t)(is_lk ? 1 : 2) * NHSD + (size_t)head * SEQ * DH;  // ku / vu
  int tid = threadIdx.x, w = tid >> 6, l = tid & 63, q = l >> 4, c = l & 15;
  const f32x4 zf = {0.f, 0.f, 0.f, 0.f};
  f32x4 tacc[2][8];
  for (int tr = 0; tr < 2; ++tr) for (int tc = 0; tc < 8; ++tc) tacc[tr][tc] = zf;
#pragma unroll
  for (int ks = 0; ks < 2; ++ks) {
    f16x8 aq[2], bf[8];
#pragma unroll
    for (int tr = 0; tr < 2; ++tr)
      aq[tr] = *(const f16x8*)(Ah + (size_t)(RB * 128 + w * 32 + tr * 16 + c) * DH + ks * 32 + q * 8);
#pragma unroll
    for (int tc = 0; tc < 8; ++tc)
      bf[tc] = *(const f16x8*)(Bh + (size_t)(CB * 128 + tc * 16 + c) * DH + ks * 32 + q * 8);
#pragma unroll
    for (int tr = 0; tr < 2; ++tr)
#pragma unroll
      for (int tc = 0; tc < 8; ++tc)
        tacc[tr][tc] = __builtin_amdgcn_mfma_f32_16x16x32_f16(aq[tr], bf[tc], tacc[tr][tc], 0, 0, 0);
  }
#pragma unroll
  for (int tr = 0; tr < 2; ++tr)
#pragma unroll
    for (int tc = 0; tc < 8; ++tc)
#pragma unroll
      for (int r = 0; r < 4; ++r) {
        int row = w * 32 + tr * 16 + q * 4 + r;
        int col = tc * 16 + c;
        int rg = RB * 128 + row, cg = CB * 128 + col;
        float v = tacc[tr][tc][r];
        f16 ov;
        if (is_lk) ov = (cg > rg) ? (f16)__builtin_amdgcn_rcpf(1.f + __expf(-v)) : (f16)(0.f);
        else       ov = (cg <= rg) ? (f16)v : (f16)(0.f);
        st[(row << 7) + (((col >> 3) ^ (row & 15)) << 3) + (col & 7)] = ov;
      }
  __syncthreads();
#pragma unroll
  for (int i = 0; i < 8; ++i) {
    int ch = i * 256 + tid;
    int ks = ch >> 9, rb = (ch >> 6) & 7, ln = ch & 63;
    int qq = ln >> 4, cc = ln & 15;
    int row = rb * 16 + cc, cchunk = ks * 4 + qq;
    f16x8 v = *(const f16x8*)(st + (row << 7) + ((cchunk ^ (row & 15)) << 3));
    *(f16x8*)(dst + (size_t)ch * 8) = v;
  }
}

// ---------------- prefix kernel: PP(K,J) = sum_{J'=K..J} lkT(K,J') @ vu(J') ----------------
__global__ __launch_bounds__(256) void k_prefix(const f16* __restrict__ lkT, const f16* __restrict__ vuF,
                                                f16* __restrict__ PPT) {
  __shared__ f16 lkb[2][16384];
  __shared__ f16 vub[2][8192];
  __shared__ f16 st[8192];
  int head = blockIdx.x >> 4, K = blockIdx.x & 15;
  int offK = 16 * K - (K * (K - 1)) / 2;
  const f16* lkh = lkT + ((size_t)(head * NTILE) << 14);
  const f16* vuh = vuF + (size_t)head * (SEQ * DH);
  f16* pph = PPT + ((size_t)(head * NTILE) << 13);
  int tid = threadIdx.x, w = tid >> 6, l = tid & 63, q = l >> 4, c = l & 15;
  f32x4 acc[2][4];
  const f32x4 zf = {0.f, 0.f, 0.f, 0.f};
  for (int tr = 0; tr < 2; ++tr) for (int tv = 0; tv < 4; ++tv) acc[tr][tv] = zf;
  // prologue: stage J=K into buf 0
  {
    const f16* lt = lkh + ((size_t)offK << 14);
#pragma unroll
    for (int i = 0; i < 8; ++i) {
      int e = (i * 256 + tid) * 8;
      __builtin_amdgcn_global_load_lds((const __attribute__((address_space(1))) void*)(lt + e),
                                       (__attribute__((address_space(3))) void*)(&lkb[0][0] + e), 16, 0, 0);
    }
    const f16* vt_ = vuh + ((size_t)K << 13);
#pragma unroll
    for (int i = 0; i < 4; ++i) {
      int e = (i * 256 + tid) * 8;
      __builtin_amdgcn_global_load_lds((const __attribute__((address_space(1))) void*)(vt_ + e),
                                       (__attribute__((address_space(3))) void*)(&vub[0][0] + e), 16, 0, 0);
    }
  }
  int pb = 0;
  for (int J = K; J < 16; ++J) {
    __syncthreads();   // buf[pb] staged; previous st re-reads complete
    if (J < 15) {      // prefetch next J into the idle buffer (overlaps MFMA + st phases)
      const f16* lt = lkh + ((size_t)(offK + (J + 1 - K)) << 14);
#pragma unroll
      for (int i = 0; i < 8; ++i) {
        int e = (i * 256 + tid) * 8;
        __builtin_amdgcn_global_load_lds((const __attribute__((address_space(1))) void*)(lt + e),
                                         (__attribute__((address_space(3))) void*)(&lkb[pb ^ 1][0] + e), 16, 0, 0);
      }
      const f16* vt_ = vuh + ((size_t)(J + 1) << 13);
#pragma unroll
      for (int i = 0; i < 4; ++i) {
        int e = (i * 256 + tid) * 8;
        __builtin_amdgcn_global_load_lds((const __attribute__((address_space(1))) void*)(vt_ + e),
                                         (__attribute__((address_space(3))) void*)(&vub[pb ^ 1][0] + e), 16, 0, 0);
      }
    }
#pragma unroll
    for (int ks = 0; ks < 4; ++ks) {
      f16x8 af[2], bf[4];
#pragma unroll
      for (int tr = 0; tr < 2; ++tr)
        af[tr] = *(const f16x8*)(&lkb[pb][0] + ((ks * 8 + w * 2 + tr) * 64 + l) * 8);
#pragma unroll
      for (int tv = 0; tv < 4; ++tv)
        bf[tv] = *(const f16x8*)(&vub[pb][0] + ((ks * 4 + tv) * 64 + l) * 8);
#pragma unroll
      for (int tr = 0; tr < 2; ++tr)
#pragma unroll
        for (int tv = 0; tv < 4; ++tv)
          acc[tr][tv] = __builtin_amdgcn_mfma_f32_16x16x32_f16(af[tr], bf[tv], acc[tr][tv], 0, 0, 0);
    }
    // acc -> st (f16, swizzled 128x64)
#pragma unroll
    for (int tr = 0; tr < 2; ++tr)
#pragma unroll
      for (int tv = 0; tv < 4; ++tv)
#pragma unroll
        for (int r = 0; r < 4; ++r) {
          int row = w * 32 + tr * 16 + q * 4 + r;
          int col = tv * 16 + c;
          st[(row << 6) + (((col >> 3) ^ (row & 7)) << 3) + (col & 7)] = (f16)acc[tr][tv][r];
        }
    __syncthreads();   // st complete (prefetch had the MFMA phase to fly)
    // st re-read in frag order -> PPT(K,J)
    f16* dst = pph + ((size_t)(offK + (J - K)) << 13);
#pragma unroll
    for (int i = 0; i < 4; ++i) {
      int slot = i * 256 + tid;
      int chunk = slot >> 6, ln = slot & 63;
      int ks2 = chunk >> 3, tc = chunk & 7, qq = ln >> 4, cc = ln & 15;
      int row = tc * 16 + cc, cch = ks2 * 4 + qq;
      f16x8 v = *(const f16x8*)(st + (row << 6) + ((cch ^ (row & 7)) << 3));
      *(f16x8*)(dst + (size_t)slot * 8) = v;
    }
    pb ^= 1;
  }
}

// ---------------- flash (R25 structure): R24 pipeline + 8 waves x 16 rows ----------------
__global__ __launch_bounds__(512, 1) void k_flash(const f16* __restrict__ q6, const f16* __restrict__ t1dT,
                                                  const f16* __restrict__ lkT, const f16* __restrict__ PPT,
                                                  f16* __restrict__ pO, float* __restrict__ pML) {
  __shared__ f16 Sb[2][40960];      // 2 x 80KB: each = lk(0) | pp(16384) | kc(24576) | vt(32768)
  int bid = blockIdx.x;
  int big = bid & 1;
  int rest = bid >> 1;
  int head = ((rest & 7) << 1) | ((rest >> 3) & 1);
  int r2 = 31 - (rest >> 4);        // reversed: big pairs dispatch first
  int a = 0, s = 0;
  {
    int acc = 0;
    for (int aa = 0; aa < 8; ++aa) {
      int si = ns2(aa);
      if (r2 >= acc && r2 < acc + si) { a = aa; s = r2 - acc; }
      acc += si;
    }
  }
  int I1 = 2 * a + 1;
  int S_ = ns2(a);
  int Ktot = I1 + 1;
  int K0 = (Ktot * s) / S_, K1 = (Ktot * (s + 1)) / S_;
  int IB = 2 * a + big;             // this block's I-tile
  int Kbeg = (K0 < IB + 1) ? K0 : IB + 1;
  int Kend = (K1 < IB + 1) ? K1 : IB + 1;

  const f16* qc  = q6 + (size_t)3 * NHSD + (size_t)head * SEQ * DH;   // pre-scaled
  const f16* kcF = q6 + (size_t)4 * NHSD + (size_t)head * (SEQ * DH);
  const f16* vtF = q6 + (size_t)5 * NHSD + (size_t)head * (SEQ * DH);
  int tid = threadIdx.x, w = tid >> 6, l = tid & 63, q = l >> 4, c = l & 15;
  const f16* lkh = lkT + ((size_t)(head * NTILE) << 14);
  const f16* pph = PPT + ((size_t)(head * NTILE) << 13);
  const f16* t1d = t1dT + ((size_t)(head * 16 + IB) << 14);

  // per-wave constants in registers (wave w owns rows [w*16, w*16+16))
  f16x8 a_qc[2];
#pragma unroll
  for (int ks = 0; ks < 2; ++ks)
    a_qc[ks] = *(const f16x8*)(qc + (size_t)(IB * 128 + w * 16 + c) * DH + ks * 32 + q * 8);
  f16x8 a_t1[4];
#pragma unroll
  for (int ks = 0; ks < 4; ++ks)
    a_t1[ks] = *(const f16x8*)(t1d + (size_t)((ks * 8 + w) * 64 + l) * 8);

  f32x4 su[8], oacc[4];
  float m_i[4], l_i[4];
  const f32x4 zf = {0.f, 0.f, 0.f, 0.f};
  for (int tv = 0; tv < 4; ++tv) oacc[tv] = zf;
  for (int r = 0; r < 4; ++r) { m_i[r] = -INFINITY; l_i[r] = 0.f; }

  // prologue: stage K=Kbeg into buf 0
  if (Kbeg < Kend) {
    int K = Kbeg;
    int offK = 16 * K - (K * (K - 1)) / 2;
    f16* D = &Sb[0][0];
    const f16* p1 = lkh + ((size_t)(offK + (IB - K)) << 14);
#pragma unroll
    for (int i = 0; i < 4; ++i) {
      int e = (i * 512 + tid) * 8;
      __builtin_amdgcn_global_load_lds((const __attribute__((address_space(1))) void*)(p1 + e),
                                       (__attribute__((address_space(3))) void*)(D + e), 16, 0, 0);
    }
    if (K < IB) {
      const f16* pp = pph + ((size_t)(offK + (IB - 1 - K)) << 13);
#pragma unroll
      for (int i = 0; i < 2; ++i) {
        int e = (i * 512 + tid) * 8;
        __builtin_amdgcn_global_load_lds((const __attribute__((address_space(1))) void*)(pp + e),
                                         (__attribute__((address_space(3))) void*)(D + 16384 + e), 16, 0, 0);
      }
    }
    const f16* kt_ = kcF + ((size_t)K << 13);
    const f16* vv_ = vtF + ((size_t)K << 13);
#pragma unroll
    for (int i = 0; i < 2; ++i) {
      int e = (i * 512 + tid) * 8;
      __builtin_amdgcn_global_load_lds((const __attribute__((address_space(1))) void*)(kt_ + e),
                                       (__attribute__((address_space(3))) void*)(D + 24576 + e), 16, 0, 0);
      __builtin_amdgcn_global_load_lds((const __attribute__((address_space(1))) void*)(vv_ + e),
                                       (__attribute__((address_space(3))) void*)(D + 32768 + e), 16, 0, 0);
    }
  }

  int cur = 0;
  for (int K = Kbeg; K < Kend; ++K) {
#pragma unroll
    for (int tc = 0; tc < 8; ++tc) su[tc] = zf;

    __syncthreads();   // top: buf[cur]'s stage drained; prior PV reads of buf[cur^1] ordered

    // issue next-K stage into buf[cur^1] — flies through the entire compute phase
    if (K + 1 < Kend) {
      int Kn = K + 1;
      int offKn = 16 * Kn - (Kn * (Kn - 1)) / 2;
      f16* D = &Sb[cur ^ 1][0];
      const f16* p1 = lkh + ((size_t)(offKn + (IB - Kn)) << 14);
#pragma unroll
      for (int i = 0; i < 4; ++i) {
        int e = (i * 512 + tid) * 8;
        __builtin_amdgcn_global_load_lds((const __attribute__((address_space(1))) void*)(p1 + e),
                                         (__attribute__((address_space(3))) void*)(D + e), 16, 0, 0);
      }
      if (Kn < IB) {
        const f16* pp = pph + ((size_t)(offKn + (IB - 1 - Kn)) << 13);
#pragma unroll
        for (int i = 0; i < 2; ++i) {
          int e = (i * 512 + tid) * 8;
          __builtin_amdgcn_global_load_lds((const __attribute__((address_space(1))) void*)(pp + e),
                                           (__attribute__((address_space(3))) void*)(D + 16384 + e), 16, 0, 0);
        }
      }
      const f16* kt_ = kcF + ((size_t)Kn << 13);
      const f16* vv_ = vtF + ((size_t)Kn << 13);
#pragma unroll
      for (int i = 0; i < 2; ++i) {
        int e = (i * 512 + tid) * 8;
        __builtin_amdgcn_global_load_lds((const __attribute__((address_space(1))) void*)(kt_ + e),
                                         (__attribute__((address_space(3))) void*)(D + 24576 + e), 16, 0, 0);
        __builtin_amdgcn_global_load_lds((const __attribute__((address_space(1))) void*)(vv_ + e),
                                         (__attribute__((address_space(3))) void*)(D + 32768 + e), 16, 0, 0);
      }
    }

    f16* bufc = &Sb[cur][0];
    // PP term: su += a_qc @ PP(K, IB-1)
    if (K < IB) {
      const f16* ppb = bufc + 16384;
#pragma unroll
      for (int ks = 0; ks < 2; ++ks) {
        f16x8 bf[8];
#pragma unroll
        for (int tc = 0; tc < 8; ++tc)
          bf[tc] = *(const f16x8*)(ppb + ((ks * 8 + tc) * 64 + l) * 8);
#pragma unroll
        for (int tc = 0; tc < 8; ++tc)
          su[tc] = __builtin_amdgcn_mfma_f32_16x16x32_f16(a_qc[ks], bf[tc], su[tc], 0, 0, 0);
      }
    }
    // t1d term: su += a_t1 @ lk(K, IB)^T
    {
      __builtin_amdgcn_s_setprio(1);
#pragma unroll
      for (int ks = 0; ks < 4; ++ks) {
        f16x8 bf[8];
#pragma unroll
        for (int tc = 0; tc < 8; ++tc)
          bf[tc] = *(const f16x8*)(bufc + ((ks * 8 + tc) * 64 + l) * 8);
#pragma unroll
        for (int tc = 0; tc < 8; ++tc)
          su[tc] = __builtin_amdgcn_mfma_f32_16x16x32_f16(a_t1[ks], bf[tc], su[tc], 0, 0, 0);
      }
      __builtin_amdgcn_s_setprio(0);
    }
    // scores = Sc - silu(Su)
#pragma unroll
    for (int tc = 0; tc < 8; ++tc)
#pragma unroll
      for (int r = 0; r < 4; ++r) {
        float v = su[tc][r];
        su[tc][r] = -v * __builtin_amdgcn_rcpf(1.f + __expf(-v));
      }
    {
      const f16* skc = bufc + 24576;
#pragma unroll
      for (int ks = 0; ks < 2; ++ks) {
        f16x8 bk[8];
#pragma unroll
        for (int tc = 0; tc < 8; ++tc)
          bk[tc] = *(const f16x8*)(skc + ((ks * 8 + tc) * 64 + l) * 8);
#pragma unroll
        for (int tc = 0; tc < 8; ++tc)
          su[tc] = __builtin_amdgcn_mfma_f32_16x16x32_f16(a_qc[ks], bk[tc], su[tc], 0, 0, 0);
      }
    }
    if (K == IB) {     // strict causal mask on the diagonal block
#pragma unroll
      for (int tc = 0; tc < 8; ++tc)
#pragma unroll
        for (int r = 0; r < 4; ++r) {
          int rg = w * 16 + q * 4 + r;
          int cg = tc * 16 + c;
          if (cg > rg) su[tc][r] = -INFINITY;
        }
    }
    // online softmax
#pragma unroll
    for (int r = 0; r < 4; ++r) {
      float mx = su[0][r];
#pragma unroll
      for (int tc = 1; tc < 8; ++tc) mx = fmaxf(mx, su[tc][r]);
      mx = fmaxf(mx, __shfl_xor(mx, 1)); mx = fmaxf(mx, __shfl_xor(mx, 2));
      mx = fmaxf(mx, __shfl_xor(mx, 4)); mx = fmaxf(mx, __shfl_xor(mx, 8));
      float mnew  = fmaxf(m_i[r], mx);
      float alpha = __expf(m_i[r] - mnew);
      float ssum = 0.f;
#pragma unroll
      for (int tc = 0; tc < 8; ++tc) {
        float pp = __expf(su[tc][r] - mnew);
        su[tc][r] = pp;
        ssum += pp;
      }
      ssum += __shfl_xor(ssum, 1); ssum += __shfl_xor(ssum, 2);
      ssum += __shfl_xor(ssum, 4); ssum += __shfl_xor(ssum, 8);
      l_i[r] = l_i[r] * alpha + ssum;
      m_i[r] = mnew;
#pragma unroll
      for (int tv = 0; tv < 4; ++tv) oacc[tv][r] *= alpha;
    }
    // join barrier: lgkmcnt-only (keeps next-K stage in flight).
    asm volatile("s_waitcnt lgkmcnt(0)" ::: "memory");
    __builtin_amdgcn_sched_barrier(0);
    __builtin_amdgcn_s_barrier();
    __builtin_amdgcn_sched_barrier(0);
    // P -> Pb (= bufc lk region; own 16-row region of the 128-row buffer)
#pragma unroll
    for (int tc = 0; tc < 8; ++tc)
#pragma unroll
      for (int r = 0; r < 4; ++r) {
        int row = w * 16 + q * 4 + r;    // 0..127
        int col = tc * 16 + c;
        bufc[(row << 7) + (((col >> 3) ^ (row & 15)) << 3) + (col & 7)] = (f16)su[tc][r];
      }
    // PV: A = P (own rows), B = staged vt
    {
      const f16* svt = bufc + 32768;
#pragma unroll
      for (int ks = 0; ks < 4; ++ks) {
        int ck = ks * 4 + q;
        f16x8 ap, bv[4];
        ap = *(const f16x8*)(bufc + ((w * 16 + c) << 7) + ((ck ^ c) << 3));
#pragma unroll
        for (int tv = 0; tv < 4; ++tv)
          bv[tv] = *(const f16x8*)(svt + ((ks * 4 + tv) * 64 + l) * 8);
#pragma unroll
        for (int tv = 0; tv < 4; ++tv)
          oacc[tv] = __builtin_amdgcn_mfma_f32_16x16x32_f16(ap, bv[tv], oacc[tv], 0, 0, 0);
      }
    }
    cur ^= 1;
  }

  // ---- unnormalized partial: slot = head*64 + prefix(IB) + s (empty ranges write m=-inf) ----
  int slot = head * SLOTS_PER_HEAD + slot_base(IB) + s;
  f16* po = pO + (size_t)slot * (128 * 64);
  float* pml = pML + (size_t)slot * 256;
  if (c == 0) {
#pragma unroll
    for (int r = 0; r < 4; ++r) {
      int row = w * 16 + q * 4 + r;
      pml[row] = m_i[r];
      pml[128 + row] = l_i[r];
    }
  }
#pragma unroll
  for (int tv = 0; tv < 4; ++tv)
#pragma unroll
    for (int r = 0; r < 4; ++r) {
      int row = w * 16 + q * 4 + r;
      int col = tv * 16 + c;
      po[row * 64 + col] = (f16)oacc[tv][r];
    }
}

// ---------------- merge partials -> oh [2048][1024] f16 ----------------
__global__ __launch_bounds__(256) void k_merge(const f16* __restrict__ pO, const float* __restrict__ pML,
                                               f16* __restrict__ oh) {
  int head = blockIdx.x >> 4, I = blockIdx.x & 15;
  int S_ = ns2(I >> 1);
  int tid = threadIdx.x;
  int row = tid >> 1, half = tid & 1;
  int base = head * SLOTS_PER_HEAD + slot_base(I);
  float m[MAXS], lv[MAXS];
  float mstar = -INFINITY;
#pragma unroll
  for (int s = 0; s < MAXS; ++s)
    if (s < S_) {
      m[s] = pML[(size_t)(base + s) * 256 + row];
      lv[s] = pML[(size_t)(base + s) * 256 + 128 + row];
      mstar = fmaxf(mstar, m[s]);
    }
  float wt[MAXS];
  float lsum = 0.f;
#pragma unroll
  for (int s = 0; s < MAXS; ++s)
    if (s < S_) {
      wt[s] = __expf(m[s] - mstar);   // empty partials (m=-inf) get weight 0
      lsum += lv[s] * wt[s];
    }
  float rinv = __builtin_amdgcn_rcpf(lsum);
#pragma unroll
  for (int cc = 0; cc < 32; cc += 8) {
    float acc[8] = {0.f, 0.f, 0.f, 0.f, 0.f, 0.f, 0.f, 0.f};
#pragma unroll
    for (int s = 0; s < MAXS; ++s)
      if (s < S_) {
        f16x8 v = *(const f16x8*)(pO + (size_t)(base + s) * 8192 + row * 64 + half * 32 + cc);
#pragma unroll
        for (int e = 0; e < 8; ++e) acc[e] += wt[s] * (float)v[e];
      }
    f16x8 o;
#pragma unroll
    for (int e = 0; e < 8; ++e) o[e] = (f16)(acc[e] * rinv);
    *(f16x8*)(oh + (size_t)(I * 128 + row) * DIM + head * 64 + half * 32 + cc) = o;
  }
}

// ---------------- final GEMM (R25 config): oh[2048,1024] @ WoT^T -> fp32, 128x128 tiles ----------------
__global__ __launch_bounds__(256) void k_gemm_out(const f16* __restrict__ A, const f16* __restrict__ B,
                                                  float* __restrict__ out) {
  __shared__ f16 sa[128 * 72];
  __shared__ f16 sb[128 * 72];
  int bx = blockIdx.x, by = blockIdx.y;
  int tid = threadIdx.x, w = tid >> 6, l = tid & 63, q = l >> 4, c = l & 15;
  f32x4 acc[2][8];
  const f32x4 zf = {0.f, 0.f, 0.f, 0.f};
  for (int i = 0; i < 2; ++i) for (int j = 0; j < 8; ++j) acc[i][j] = zf;
  for (int kt = 0; kt < DIM / 64; ++kt) {
    __syncthreads();
#pragma unroll
    for (int it = 0; it < 4; ++it) {
      int idx = it * 256 + tid; int r = idx >> 3, ch = idx & 7;
      *(float4*)(sa + r * 72 + ch * 8) = *(const float4*)(A + (size_t)(by * 128 + r) * DIM + kt * 64 + ch * 8);
      *(float4*)(sb + r * 72 + ch * 8) = *(const float4*)(B + (size_t)(bx * 128 + r) * DIM + kt * 64 + ch * 8);
    }
    __syncthreads();
#pragma unroll
    for (int ks = 0; ks < 2; ++ks) {
      f16x8 af[2], bf[8];
#pragma unroll
      for (int tr = 0; tr < 2; ++tr) af[tr] = *(const f16x8*)(sa + (w * 32 + tr * 16 + c) * 72 + ks * 32 + q * 8);
#pragma unroll
      for (int tc = 0; tc < 8; ++tc) bf[tc] = *(const f16x8*)(sb + (tc * 16 + c) * 72 + ks * 32 + q * 8);
#pragma unroll
      for (int tr = 0; tr < 2; ++tr)
#pragma unroll
        for (int tc = 0; tc < 8; ++tc)
          acc[tr][tc] = __builtin_amdgcn_mfma_f32_16x16x32_f16(af[tr], bf[tc], acc[tr][tc], 0, 0, 0);
    }
  }
#pragma unroll
  for (int tr = 0; tr < 2; ++tr)
#pragma unroll
    for (int tc = 0; tc < 8; ++tc)
#pragma unroll
      for (int r = 0; r < 4; ++r) {
        int row = by * 128 + w * 32 + tr * 16 + q * 4 + r;
        int col = bx * 128 + tc * 16 + c;
        out[(size_t)row * DIM + col] = acc[tr][tc][r];
      }
}

extern "C" void kernel_launch(void* const* d_in, const int* in_sizes, int n_in,
                              void* d_out, int out_size, void* d_ws, size_t ws_size,
                              hipStream_t stream) {
  const float* x  = (const float*)d_in[0];
  const float* Wq = (const float*)d_in[1];
  const float* Wo = (const float*)d_in[2];
  float* out = (float*)d_out;

  f16* ws = (f16*)d_ws;
  size_t off = 0;
  f16* q6   = ws + off; off += (size_t)6 * NHSD;                        // 25.2 MB
  f16* vuF  = ws + off; off += (size_t)NHSD;                            // 4.2 MB (vu^T frag tiles)
  f16* xhT  = ws + off; off += (size_t)SEQ * DIM;                       // 4.2 MB
  f16* WqTf = ws + off; off += (size_t)NCOLS * DIM;                     // 12.6 MB
  f16* WoT  = ws + off; off += (size_t)DIM * DIM;                       // 2.1 MB
  f16* oh   = ws + off; off += (size_t)SEQ * DIM;                       // 4.2 MB
  f16* pO   = ws + off; off += (size_t)NH * SLOTS_PER_HEAD * 128 * 64;  // 16.8 MB
  f16* lkT  = ws + off; off += (size_t)NH * NTILE * 128 * 128;          // 71.3 MB
  f16* t1dT = ws + off; off += (size_t)NH * 16 * 128 * 128;             // 8.4 MB (diag t1 only)
  f16* PPT  = ws + off; off += (size_t)NH * NTILE * 128 * 64;           // 35.7 MB (prefix tiles)
  float* pML = (float*)(ws + off); off += (size_t)NH * SLOTS_PER_HEAD * 256 * 2; // 1.05 MB
  // total ~186 MB of workspace

  k_prepA<<<dim3(16, 16), 256, 0, stream>>>(x, xhT);
  k_prepB<<<dim3(16, 48), 256, 0, stream>>>(Wq, WqTf);
  k_tcast<<<dim3(DIM / 64, DIM / 64), 256, 0, stream>>>(Wo, WoT, DIM, DIM);
  k_gemm_qkv<<<dim3(NCOLS / 128, SEQ / 128), 256, 0, stream>>>(xhT, WqTf, q6, vuF);
  k_t1lk<<<NH * 152, 256, 0, stream>>>(q6, t1dT, lkT);
  k_prefix<<<NH * 16, 256, 0, stream>>>(lkT, vuF, PPT);
  k_flash<<<NH * 64, 512, 0, stream>>>(q6, t1dT, lkT, PPT, pO, pML);
  k_merge<<<NH * 16, 256, 0, stream>>>(pO, pML, oh);
  k_gemm_out<<<dim3(DIM / 128, SEQ / 128), 256, 0, stream>>>(oh, WoT, out);
}

// Round 15
// 307.430 us; speedup vs baseline: 1.0975x; 1.0511x over previous
//
#include <hip/hip_runtime.h>
#include <math.h>

typedef _Float16 f16;
typedef _Float16 f16x4 __attribute__((ext_vector_type(4)));
typedef _Float16 f16x8 __attribute__((ext_vector_type(8)));
typedef float f32x4 __attribute__((ext_vector_type(4)));

#define SEQ   2048
#define DIM   1024
#define NH    16
#define DH    64
#define NCOLS 6144
#define NHSD  (NH*SEQ*DH)   /* 2,097,152 elements per qkv sub-tensor */
#define NTILE 136           /* lk tiles per head (triangular) */
#define MAXS  4
#define SLOTS_PER_HEAD 40   /* sum over I of NS2[I>>1] */

// R29 split table: per-K cost is uniform post-R20, so splits ~= Ktot/4 (was J-loop-weighted).
// pair a = (I0=2a, I1=2a+1); NS2 K-splits per pair. sum = 20 -> flash grid = NH*20*2 = 640.
__device__ __forceinline__ int ns2(int a) {
  const int NS2[8] = {1,1,2,2,3,3,4,4};
  return NS2[a];
}
__device__ __forceinline__ int slot_base(int I) {  // prefix of NS2[I'>>1] over I' < I
  const int PF[16] = {0,1,2,3,4,6,8,10,12,15,18,21,24,28,32,36};
  return PF[I];
}

// ------------- transpose + cast: out[c][r] = (f16) in[r][c], in is R x C (Wo only) -------------
__global__ __launch_bounds__(256) void k_tcast(const float* __restrict__ in, f16* __restrict__ out,
                                               int R, int C) {
  __shared__ f16 t[64 * 66];
  int bc = blockIdx.x, br = blockIdx.y;
  for (int it = 0; it < 16; ++it) {
    int idx = it * 256 + threadIdx.x;
    int r = idx >> 6, c = idx & 63;
    t[r * 66 + c] = (f16)in[(size_t)(br * 64 + r) * C + bc * 64 + c];
  }
  __syncthreads();
  for (int it = 0; it < 16; ++it) {
    int idx = it * 256 + threadIdx.x;
    int oc = idx >> 6, orr = idx & 63;
    out[(size_t)(bc * 64 + oc) * R + br * 64 + orr] = t[orr * 66 + oc];
  }
}

// ---- prepA: cast x (f32) into A-frag-chunk tiles ----
__global__ __launch_bounds__(256) void k_prepA(const float* __restrict__ x, f16* __restrict__ xhT) {
  int kt = blockIdx.x, by = blockIdx.y;
  f16* dst = xhT + ((size_t)(by * 16 + kt) << 13);
  int tid = threadIdx.x;
#pragma unroll
  for (int i = 0; i < 4; ++i) {
    int idx = i * 256 + tid;
    int chunk = idx >> 6, lane = idx & 63;
    int rb = chunk & 7, ks = chunk >> 3;
    int row = by * 128 + rb * 16 + (lane & 15);
    int kk = kt * 64 + ks * 32 + ((lane >> 4) << 3);
    const float* p = x + (size_t)row * DIM + kk;
    float4 lo = *(const float4*)p, hi = *(const float4*)(p + 4);
    f16x8 h;
    h[0] = (f16)lo.x; h[1] = (f16)lo.y; h[2] = (f16)lo.z; h[3] = (f16)lo.w;
    h[4] = (f16)hi.x; h[5] = (f16)hi.y; h[6] = (f16)hi.z; h[7] = (f16)hi.w;
    *(f16x8*)(dst + (size_t)idx * 8) = h;
  }
}

// ---- prepB (LDS-transpose): Wq[k][n] -> B-frag-chunk tiles ----
__global__ __launch_bounds__(256) void k_prepB(const float* __restrict__ Wq, f16* __restrict__ WqTf) {
  __shared__ f16 sw[64 * 130];
  int kt = blockIdx.x, bx = blockIdx.y;
  int tid = threadIdx.x;
#pragma unroll
  for (int it = 0; it < 8; ++it) {
    int idx = it * 256 + tid;          // 0..2047
    int r = idx >> 5, c4 = idx & 31;   // row, float4-chunk
    float4 v = *(const float4*)(Wq + (size_t)(kt * 64 + r) * NCOLS + bx * 128 + c4 * 4);
    f16* d = sw + r * 130 + c4 * 4;
    d[0] = (f16)v.x; d[1] = (f16)v.y; d[2] = (f16)v.z; d[3] = (f16)v.w;
  }
  __syncthreads();
  f16* dst = WqTf + ((size_t)(bx * 16 + kt) << 13);
#pragma unroll
  for (int i = 0; i < 4; ++i) {
    int idx = i * 256 + tid;
    int chunk = idx >> 6, lane = idx & 63;
    int rb = chunk & 7, ks = chunk >> 3;
    int nl = rb * 16 + (lane & 15);
    int kl = ks * 32 + ((lane >> 4) << 3);
    f16x8 h;
#pragma unroll
    for (int j = 0; j < 8; ++j) h[j] = sw[(kl + j) * 130 + nl];
    *(f16x8*)(dst + (size_t)idx * 8) = h;
  }
}

// ---------------- qkv GEMM (double-buffered K-pipeline, one barrier per step) ----------------
__global__ __launch_bounds__(256) void k_gemm_qkv(const f16* __restrict__ xhT, const f16* __restrict__ WqTf,
                                                  f16* __restrict__ q6, f16* __restrict__ vuF) {
  __shared__ f16 sa[2][8192];
  __shared__ f16 sb[2][8192];
  int bx = blockIdx.x, by = blockIdx.y;
  int tid = threadIdx.x, w = tid >> 6, l = tid & 63, q = l >> 4, c = l & 15;
  f32x4 acc[2][8];
  const f32x4 zf = {0.f, 0.f, 0.f, 0.f};
  for (int i = 0; i < 2; ++i) for (int j = 0; j < 8; ++j) acc[i][j] = zf;

  // prologue: stage kt=0 into buf 0
  {
    const f16* ta = xhT + ((size_t)(by * 16) << 13);
    const f16* tb = WqTf + ((size_t)(bx * 16) << 13);
#pragma unroll
    for (int i = 0; i < 4; ++i) {
      int e = (i * 256 + tid) * 8;
      __builtin_amdgcn_global_load_lds((const __attribute__((address_space(1))) void*)(ta + e),
                                       (__attribute__((address_space(3))) void*)(&sa[0][0] + e), 16, 0, 0);
      __builtin_amdgcn_global_load_lds((const __attribute__((address_space(1))) void*)(tb + e),
                                       (__attribute__((address_space(3))) void*)(&sb[0][0] + e), 16, 0, 0);
    }
  }
  int cur = 0;
  for (int kt = 0; kt < 16; ++kt) {
    __syncthreads();   // buf[cur] staged (vmcnt drained); prior reads of buf[cur^1] ordered
    if (kt + 1 < 16) { // issue next-K stage into the idle buffer — flies through the MFMA phase
      const f16* ta = xhT + ((size_t)(by * 16 + kt + 1) << 13);
      const f16* tb = WqTf + ((size_t)(bx * 16 + kt + 1) << 13);
#pragma unroll
      for (int i = 0; i < 4; ++i) {
        int e = (i * 256 + tid) * 8;
        __builtin_amdgcn_global_load_lds((const __attribute__((address_space(1))) void*)(ta + e),
                                         (__attribute__((address_space(3))) void*)(&sa[cur ^ 1][0] + e), 16, 0, 0);
        __builtin_amdgcn_global_load_lds((const __attribute__((address_space(1))) void*)(tb + e),
                                         (__attribute__((address_space(3))) void*)(&sb[cur ^ 1][0] + e), 16, 0, 0);
      }
    }
#pragma unroll
    for (int ks = 0; ks < 2; ++ks) {
      f16x8 af[2], bf[8];
#pragma unroll
      for (int tr = 0; tr < 2; ++tr)
        af[tr] = *(const f16x8*)(&sa[cur][0] + ((ks * 8 + w * 2 + tr) * 64 + l) * 8);
#pragma unroll
      for (int tc = 0; tc < 8; ++tc)
        bf[tc] = *(const f16x8*)(&sb[cur][0] + ((ks * 8 + tc) * 64 + l) * 8);
#pragma unroll
      for (int tr = 0; tr < 2; ++tr)
#pragma unroll
        for (int tc = 0; tc < 8; ++tc)
          acc[tr][tc] = __builtin_amdgcn_mfma_f32_16x16x32_f16(af[tr], bf[tc], acc[tr][tc], 0, 0, 0);
    }
    cur ^= 1;
  }
  // epilogue scatter
#pragma unroll
  for (int tr = 0; tr < 2; ++tr)
#pragma unroll
    for (int tc = 0; tc < 8; ++tc)
#pragma unroll
      for (int r = 0; r < 4; ++r) {
        int row = by * 128 + w * 32 + tr * 16 + q * 4 + r;
        int col = bx * 128 + tc * 16 + c;
        float v = acc[tr][tc][r];
        int t = col >> 10, head = (col >> 6) & 15, dh = col & 63;
        if (t == 0 || t == 3) v *= 0.125f;
        f16 hv = (f16)v;
        if (t == 4) {
          size_t addr = (size_t)4 * NHSD + (size_t)head * (SEQ * DH) + ((size_t)(row >> 7) << 13)
                      + (size_t)(((((dh >> 5) << 3) + ((row >> 4) & 7)) * 64
                                  + ((((dh >> 3) & 3) << 4) | (row & 15))) * 8 + (dh & 7));
          q6[addr] = hv;
        } else if (t == 5) {
          size_t addr = (size_t)5 * NHSD + (size_t)head * (SEQ * DH) + ((size_t)(row >> 7) << 13)
                      + (size_t)((((((row >> 5) & 3) << 2) + (dh >> 4)) * 64
                                  + ((((row >> 3) & 3) << 4) | (dh & 15))) * 8 + (row & 7));
          q6[addr] = hv;
        } else if (t == 2) {
          q6[(size_t)2 * NHSD + (size_t)(head * SEQ + row) * DH + dh] = hv;
          size_t fa = ((size_t)(row >> 7) << 13)
                    + (size_t)((((((row >> 5) & 3) << 2) + (dh >> 4)) * 64
                                + ((((row >> 3) & 3) << 4) | (dh & 15))) * 8 + (row & 7));
          vuF[(size_t)head * (SEQ * DH) + fa] = hv;
        } else {
          q6[(size_t)t * NHSD + (size_t)(head * SEQ + row) * DH + dh] = hv;
        }
      }
}

// ---------------- tile producer: t1 DIAGONAL tiles only (16/head) + all lk tiles ----------------
__global__ __launch_bounds__(256) void k_t1lk(const f16* __restrict__ q6, f16* __restrict__ t1dT,
                                              f16* __restrict__ lkT) {
  __shared__ f16 st[128 * 128];
  int head = blockIdx.x / 152;
  int p = blockIdx.x % 152;
  bool is_lk = (p >= 16);
  int RB, CB;
  f16* dst;
  if (is_lk) {
    int p2 = p - 16;
    int K = 0, off = 0;
    while (off + (16 - K) <= p2) { off += 16 - K; ++K; }
    RB = K; CB = K + (p2 - off);
    dst = lkT + ((size_t)(head * NTILE + p2) << 14);
  } else {
    RB = p; CB = p;   // diagonal t1 tile
    dst = t1dT + ((size_t)(head * 16 + p) << 14);
  }
  const f16* Ah = q6 + (size_t)(is_lk ? 0 : 3) * NHSD + (size_t)head * SEQ * DH;  // qu_s / qc_s
  const f16* Bh = q6 + (size_t)(is_lk ? 1 : 2) * NHSD + (size_t)head * SEQ * DH;  // ku / vu
  int tid = threadIdx.x, w = tid >> 6, l = tid & 63, q = l >> 4, c = l & 15;
  const f32x4 zf = {0.f, 0.f, 0.f, 0.f};
  f32x4 tacc[2][8];
  for (int tr = 0; tr < 2; ++tr) for (int tc = 0; tc < 8; ++tc) tacc[tr][tc] = zf;
#pragma unroll
  for (int ks = 0; ks < 2; ++ks) {
    f16x8 aq[2], bf[8];
#pragma unroll
    for (int tr = 0; tr < 2; ++tr)
      aq[tr] = *(const f16x8*)(Ah + (size_t)(RB * 128 + w * 32 + tr * 16 + c) * DH + ks * 32 + q * 8);
#pragma unroll
    for (int tc = 0; tc < 8; ++tc)
      bf[tc] = *(const f16x8*)(Bh + (size_t)(CB * 128 + tc * 16 + c) * DH + ks * 32 + q * 8);
#pragma unroll
    for (int tr = 0; tr < 2; ++tr)
#pragma unroll
      for (int tc = 0; tc < 8; ++tc)
        tacc[tr][tc] = __builtin_amdgcn_mfma_f32_16x16x32_f16(aq[tr], bf[tc], tacc[tr][tc], 0, 0, 0);
  }
#pragma unroll
  for (int tr = 0; tr < 2; ++tr)
#pragma unroll
    for (int tc = 0; tc < 8; ++tc)
#pragma unroll
      for (int r = 0; r < 4; ++r) {
        int row = w * 32 + tr * 16 + q * 4 + r;
        int col = tc * 16 + c;
        int rg = RB * 128 + row, cg = CB * 128 + col;
        float v = tacc[tr][tc][r];
        f16 ov;
        if (is_lk) ov = (cg > rg) ? (f16)__builtin_amdgcn_rcpf(1.f + __expf(-v)) : (f16)(0.f);
        else       ov = (cg <= rg) ? (f16)v : (f16)(0.f);
        st[(row << 7) + (((col >> 3) ^ (row & 15)) << 3) + (col & 7)] = ov;
      }
  __syncthreads();
#pragma unroll
  for (int i = 0; i < 8; ++i) {
    int ch = i * 256 + tid;
    int ks = ch >> 9, rb = (ch >> 6) & 7, ln = ch & 63;
    int qq = ln >> 4, cc = ln & 15;
    int row = rb * 16 + cc, cchunk = ks * 4 + qq;
    f16x8 v = *(const f16x8*)(st + (row << 7) + ((cchunk ^ (row & 15)) << 3));
    *(f16x8*)(dst + (size_t)ch * 8) = v;
  }
}

// ---------------- prefix kernel: PP(K,J) = sum_{J'=K..J} lkT(K,J') @ vu(J') ----------------
__global__ __launch_bounds__(256) void k_prefix(const f16* __restrict__ lkT, const f16* __restrict__ vuF,
                                                f16* __restrict__ PPT) {
  __shared__ f16 lkb[2][16384];
  __shared__ f16 vub[2][8192];
  __shared__ f16 st[8192];
  int head = blockIdx.x >> 4, K = blockIdx.x & 15;
  int offK = 16 * K - (K * (K - 1)) / 2;
  const f16* lkh = lkT + ((size_t)(head * NTILE) << 14);
  const f16* vuh = vuF + (size_t)head * (SEQ * DH);
  f16* pph = PPT + ((size_t)(head * NTILE) << 13);
  int tid = threadIdx.x, w = tid >> 6, l = tid & 63, q = l >> 4, c = l & 15;
  f32x4 acc[2][4];
  const f32x4 zf = {0.f, 0.f, 0.f, 0.f};
  for (int tr = 0; tr < 2; ++tr) for (int tv = 0; tv < 4; ++tv) acc[tr][tv] = zf;
  // prologue: stage J=K into buf 0
  {
    const f16* lt = lkh + ((size_t)offK << 14);
#pragma unroll
    for (int i = 0; i < 8; ++i) {
      int e = (i * 256 + tid) * 8;
      __builtin_amdgcn_global_load_lds((const __attribute__((address_space(1))) void*)(lt + e),
                                       (__attribute__((address_space(3))) void*)(&lkb[0][0] + e), 16, 0, 0);
    }
    const f16* vt_ = vuh + ((size_t)K << 13);
#pragma unroll
    for (int i = 0; i < 4; ++i) {
      int e = (i * 256 + tid) * 8;
      __builtin_amdgcn_global_load_lds((const __attribute__((address_space(1))) void*)(vt_ + e),
                                       (__attribute__((address_space(3))) void*)(&vub[0][0] + e), 16, 0, 0);
    }
  }
  int pb = 0;
  for (int J = K; J < 16; ++J) {
    __syncthreads();   // buf[pb] staged; previous st re-reads complete
    if (J < 15) {      // prefetch next J into the idle buffer (overlaps MFMA + st phases)
      const f16* lt = lkh + ((size_t)(offK + (J + 1 - K)) << 14);
#pragma unroll
      for (int i = 0; i < 8; ++i) {
        int e = (i * 256 + tid) * 8;
        __builtin_amdgcn_global_load_lds((const __attribute__((address_space(1))) void*)(lt + e),
                                         (__attribute__((address_space(3))) void*)(&lkb[pb ^ 1][0] + e), 16, 0, 0);
      }
      const f16* vt_ = vuh + ((size_t)(J + 1) << 13);
#pragma unroll
      for (int i = 0; i < 4; ++i) {
        int e = (i * 256 + tid) * 8;
        __builtin_amdgcn_global_load_lds((const __attribute__((address_space(1))) void*)(vt_ + e),
                                         (__attribute__((address_space(3))) void*)(&vub[pb ^ 1][0] + e), 16, 0, 0);
      }
    }
#pragma unroll
    for (int ks = 0; ks < 4; ++ks) {
      f16x8 af[2], bf[4];
#pragma unroll
      for (int tr = 0; tr < 2; ++tr)
        af[tr] = *(const f16x8*)(&lkb[pb][0] + ((ks * 8 + w * 2 + tr) * 64 + l) * 8);
#pragma unroll
      for (int tv = 0; tv < 4; ++tv)
        bf[tv] = *(const f16x8*)(&vub[pb][0] + ((ks * 4 + tv) * 64 + l) * 8);
#pragma unroll
      for (int tr = 0; tr < 2; ++tr)
#pragma unroll
        for (int tv = 0; tv < 4; ++tv)
          acc[tr][tv] = __builtin_amdgcn_mfma_f32_16x16x32_f16(af[tr], bf[tv], acc[tr][tv], 0, 0, 0);
    }
    // acc -> st (f16, swizzled 128x64)
#pragma unroll
    for (int tr = 0; tr < 2; ++tr)
#pragma unroll
      for (int tv = 0; tv < 4; ++tv)
#pragma unroll
        for (int r = 0; r < 4; ++r) {
          int row = w * 32 + tr * 16 + q * 4 + r;
          int col = tv * 16 + c;
          st[(row << 6) + (((col >> 3) ^ (row & 7)) << 3) + (col & 7)] = (f16)acc[tr][tv][r];
        }
    __syncthreads();   // st complete (prefetch had the MFMA phase to fly)
    // st re-read in frag order -> PPT(K,J)
    f16* dst = pph + ((size_t)(offK + (J - K)) << 13);
#pragma unroll
    for (int i = 0; i < 4; ++i) {
      int slot = i * 256 + tid;
      int chunk = slot >> 6, ln = slot & 63;
      int ks2 = chunk >> 3, tc = chunk & 7, qq = ln >> 4, cc = ln & 15;
      int row = tc * 16 + cc, cch = ks2 * 4 + qq;
      f16x8 v = *(const f16x8*)(st + (row << 6) + ((cch ^ (row & 7)) << 3));
      *(f16x8*)(dst + (size_t)slot * 8) = v;
    }
    pb ^= 1;
  }
}

// ---------------- flash: R24/R25 pipeline + R29 balanced split-K ----------------
__global__ __launch_bounds__(512, 1) void k_flash(const f16* __restrict__ q6, const f16* __restrict__ t1dT,
                                                  const f16* __restrict__ lkT, const f16* __restrict__ PPT,
                                                  f16* __restrict__ pO, float* __restrict__ pML) {
  __shared__ f16 Sb[2][40960];      // 2 x 80KB: each = lk(0) | pp(16384) | kc(24576) | vt(32768)
  int bid = blockIdx.x;
  int big = bid & 1;
  int rest = bid >> 1;              // 0..319
  int head = rest & 15;
  int r2 = 19 - (rest >> 4);        // 0..19, big pairs dispatch first
  int a = 0, s = 0;
  {
    int acc = 0;
    for (int aa = 0; aa < 8; ++aa) {
      int si = ns2(aa);
      if (r2 >= acc && r2 < acc + si) { a = aa; s = r2 - acc; }
      acc += si;
    }
  }
  int I1 = 2 * a + 1;
  int S_ = ns2(a);
  int Ktot = I1 + 1;
  int K0 = (Ktot * s) / S_, K1 = (Ktot * (s + 1)) / S_;
  int IB = 2 * a + big;             // this block's I-tile
  int Kbeg = (K0 < IB + 1) ? K0 : IB + 1;
  int Kend = (K1 < IB + 1) ? K1 : IB + 1;

  const f16* qc  = q6 + (size_t)3 * NHSD + (size_t)head * SEQ * DH;   // pre-scaled
  const f16* kcF = q6 + (size_t)4 * NHSD + (size_t)head * (SEQ * DH);
  const f16* vtF = q6 + (size_t)5 * NHSD + (size_t)head * (SEQ * DH);
  int tid = threadIdx.x, w = tid >> 6, l = tid & 63, q = l >> 4, c = l & 15;
  const f16* lkh = lkT + ((size_t)(head * NTILE) << 14);
  const f16* pph = PPT + ((size_t)(head * NTILE) << 13);
  const f16* t1d = t1dT + ((size_t)(head * 16 + IB) << 14);

  // per-wave constants in registers (wave w owns rows [w*16, w*16+16))
  f16x8 a_qc[2];
#pragma unroll
  for (int ks = 0; ks < 2; ++ks)
    a_qc[ks] = *(const f16x8*)(qc + (size_t)(IB * 128 + w * 16 + c) * DH + ks * 32 + q * 8);
  f16x8 a_t1[4];
#pragma unroll
  for (int ks = 0; ks < 4; ++ks)
    a_t1[ks] = *(const f16x8*)(t1d + (size_t)((ks * 8 + w) * 64 + l) * 8);

  f32x4 su[8], oacc[4];
  float m_i[4], l_i[4];
  const f32x4 zf = {0.f, 0.f, 0.f, 0.f};
  for (int tv = 0; tv < 4; ++tv) oacc[tv] = zf;
  for (int r = 0; r < 4; ++r) { m_i[r] = -INFINITY; l_i[r] = 0.f; }

  // prologue: stage K=Kbeg into buf 0
  if (Kbeg < Kend) {
    int K = Kbeg;
    int offK = 16 * K - (K * (K - 1)) / 2;
    f16* D = &Sb[0][0];
    const f16* p1 = lkh + ((size_t)(offK + (IB - K)) << 14);
#pragma unroll
    for (int i = 0; i < 4; ++i) {
      int e = (i * 512 + tid) * 8;
      __builtin_amdgcn_global_load_lds((const __attribute__((address_space(1))) void*)(p1 + e),
                                       (__attribute__((address_space(3))) void*)(D + e), 16, 0, 0);
    }
    if (K < IB) {
      const f16* pp = pph + ((size_t)(offK + (IB - 1 - K)) << 13);
#pragma unroll
      for (int i = 0; i < 2; ++i) {
        int e = (i * 512 + tid) * 8;
        __builtin_amdgcn_global_load_lds((const __attribute__((address_space(1))) void*)(pp + e),
                                         (__attribute__((address_space(3))) void*)(D + 16384 + e), 16, 0, 0);
      }
    }
    const f16* kt_ = kcF + ((size_t)K << 13);
    const f16* vv_ = vtF + ((size_t)K << 13);
#pragma unroll
    for (int i = 0; i < 2; ++i) {
      int e = (i * 512 + tid) * 8;
      __builtin_amdgcn_global_load_lds((const __attribute__((address_space(1))) void*)(kt_ + e),
                                       (__attribute__((address_space(3))) void*)(D + 24576 + e), 16, 0, 0);
      __builtin_amdgcn_global_load_lds((const __attribute__((address_space(1))) void*)(vv_ + e),
                                       (__attribute__((address_space(3))) void*)(D + 32768 + e), 16, 0, 0);
    }
  }

  int cur = 0;
  for (int K = Kbeg; K < Kend; ++K) {
#pragma unroll
    for (int tc = 0; tc < 8; ++tc) su[tc] = zf;

    __syncthreads();   // top: buf[cur]'s stage drained; prior PV reads of buf[cur^1] ordered

    // issue next-K stage into buf[cur^1] — flies through the entire compute phase
    if (K + 1 < Kend) {
      int Kn = K + 1;
      int offKn = 16 * Kn - (Kn * (Kn - 1)) / 2;
      f16* D = &Sb[cur ^ 1][0];
      const f16* p1 = lkh + ((size_t)(offKn + (IB - Kn)) << 14);
#pragma unroll
      for (int i = 0; i < 4; ++i) {
        int e = (i * 512 + tid) * 8;
        __builtin_amdgcn_global_load_lds((const __attribute__((address_space(1))) void*)(p1 + e),
                                         (__attribute__((address_space(3))) void*)(D + e), 16, 0, 0);
      }
      if (Kn < IB) {
        const f16* pp = pph + ((size_t)(offKn + (IB - 1 - Kn)) << 13);
#pragma unroll
        for (int i = 0; i < 2; ++i) {
          int e = (i * 512 + tid) * 8;
          __builtin_amdgcn_global_load_lds((const __attribute__((address_space(1))) void*)(pp + e),
                                           (__attribute__((address_space(3))) void*)(D + 16384 + e), 16, 0, 0);
        }
      }
      const f16* kt_ = kcF + ((size_t)Kn << 13);
      const f16* vv_ = vtF + ((size_t)Kn << 13);
#pragma unroll
      for (int i = 0; i < 2; ++i) {
        int e = (i * 512 + tid) * 8;
        __builtin_amdgcn_global_load_lds((const __attribute__((address_space(1))) void*)(kt_ + e),
                                         (__attribute__((address_space(3))) void*)(D + 24576 + e), 16, 0, 0);
        __builtin_amdgcn_global_load_lds((const __attribute__((address_space(1))) void*)(vv_ + e),
                                         (__attribute__((address_space(3))) void*)(D + 32768 + e), 16, 0, 0);
      }
    }

    f16* bufc = &Sb[cur][0];
    // PP term: su += a_qc @ PP(K, IB-1)
    if (K < IB) {
      const f16* ppb = bufc + 16384;
#pragma unroll
      for (int ks = 0; ks < 2; ++ks) {
        f16x8 bf[8];
#pragma unroll
        for (int tc = 0; tc < 8; ++tc)
          bf[tc] = *(const f16x8*)(ppb + ((ks * 8 + tc) * 64 + l) * 8);
#pragma unroll
        for (int tc = 0; tc < 8; ++tc)
          su[tc] = __builtin_amdgcn_mfma_f32_16x16x32_f16(a_qc[ks], bf[tc], su[tc], 0, 0, 0);
      }
    }
    // t1d term: su += a_t1 @ lk(K, IB)^T
    {
      __builtin_amdgcn_s_setprio(1);
#pragma unroll
      for (int ks = 0; ks < 4; ++ks) {
        f16x8 bf[8];
#pragma unroll
        for (int tc = 0; tc < 8; ++tc)
          bf[tc] = *(const f16x8*)(bufc + ((ks * 8 + tc) * 64 + l) * 8);
#pragma unroll
        for (int tc = 0; tc < 8; ++tc)
          su[tc] = __builtin_amdgcn_mfma_f32_16x16x32_f16(a_t1[ks], bf[tc], su[tc], 0, 0, 0);
      }
      __builtin_amdgcn_s_setprio(0);
    }
    // scores = Sc - silu(Su)
#pragma unroll
    for (int tc = 0; tc < 8; ++tc)
#pragma unroll
      for (int r = 0; r < 4; ++r) {
        float v = su[tc][r];
        su[tc][r] = -v * __builtin_amdgcn_rcpf(1.f + __expf(-v));
      }
    {
      const f16* skc = bufc + 24576;
#pragma unroll
      for (int ks = 0; ks < 2; ++ks) {
        f16x8 bk[8];
#pragma unroll
        for (int tc = 0; tc < 8; ++tc)
          bk[tc] = *(const f16x8*)(skc + ((ks * 8 + tc) * 64 + l) * 8);
#pragma unroll
        for (int tc = 0; tc < 8; ++tc)
          su[tc] = __builtin_amdgcn_mfma_f32_16x16x32_f16(a_qc[ks], bk[tc], su[tc], 0, 0, 0);
      }
    }
    if (K == IB) {     // strict causal mask on the diagonal block
#pragma unroll
      for (int tc = 0; tc < 8; ++tc)
#pragma unroll
        for (int r = 0; r < 4; ++r) {
          int rg = w * 16 + q * 4 + r;
          int cg = tc * 16 + c;
          if (cg > rg) su[tc][r] = -INFINITY;
        }
    }
    // online softmax
#pragma unroll
    for (int r = 0; r < 4; ++r) {
      float mx = su[0][r];
#pragma unroll
      for (int tc = 1; tc < 8; ++tc) mx = fmaxf(mx, su[tc][r]);
      mx = fmaxf(mx, __shfl_xor(mx, 1)); mx = fmaxf(mx, __shfl_xor(mx, 2));
      mx = fmaxf(mx, __shfl_xor(mx, 4)); mx = fmaxf(mx, __shfl_xor(mx, 8));
      float mnew  = fmaxf(m_i[r], mx);
      float alpha = __expf(m_i[r] - mnew);
      float ssum = 0.f;
#pragma unroll
      for (int tc = 0; tc < 8; ++tc) {
        float pp = __expf(su[tc][r] - mnew);
        su[tc][r] = pp;
        ssum += pp;
      }
      ssum += __shfl_xor(ssum, 1); ssum += __shfl_xor(ssum, 2);
      ssum += __shfl_xor(ssum, 4); ssum += __shfl_xor(ssum, 8);
      l_i[r] = l_i[r] * alpha + ssum;
      m_i[r] = mnew;
#pragma unroll
      for (int tv = 0; tv < 4; ++tv) oacc[tv][r] *= alpha;
    }
    // join barrier: lgkmcnt-only (keeps next-K stage in flight).
    asm volatile("s_waitcnt lgkmcnt(0)" ::: "memory");
    __builtin_amdgcn_sched_barrier(0);
    __builtin_amdgcn_s_barrier();
    __builtin_amdgcn_sched_barrier(0);
    // P -> Pb (= bufc lk region; own 16-row region of the 128-row buffer)
#pragma unroll
    for (int tc = 0; tc < 8; ++tc)
#pragma unroll
      for (int r = 0; r < 4; ++r) {
        int row = w * 16 + q * 4 + r;    // 0..127
        int col = tc * 16 + c;
        bufc[(row << 7) + (((col >> 3) ^ (row & 15)) << 3) + (col & 7)] = (f16)su[tc][r];
      }
    // PV: A = P (own rows), B = staged vt
    {
      const f16* svt = bufc + 32768;
#pragma unroll
      for (int ks = 0; ks < 4; ++ks) {
        int ck = ks * 4 + q;
        f16x8 ap, bv[4];
        ap = *(const f16x8*)(bufc + ((w * 16 + c) << 7) + ((ck ^ c) << 3));
#pragma unroll
        for (int tv = 0; tv < 4; ++tv)
          bv[tv] = *(const f16x8*)(svt + ((ks * 4 + tv) * 64 + l) * 8);
#pragma unroll
        for (int tv = 0; tv < 4; ++tv)
          oacc[tv] = __builtin_amdgcn_mfma_f32_16x16x32_f16(ap, bv[tv], oacc[tv], 0, 0, 0);
      }
    }
    cur ^= 1;
  }

  // ---- unnormalized partial: slot = head*40 + prefix(IB) + s (empty ranges write m=-inf) ----
  int slot = head * SLOTS_PER_HEAD + slot_base(IB) + s;
  f16* po = pO + (size_t)slot * (128 * 64);
  float* pml = pML + (size_t)slot * 256;
  if (c == 0) {
#pragma unroll
    for (int r = 0; r < 4; ++r) {
      int row = w * 16 + q * 4 + r;
      pml[row] = m_i[r];
      pml[128 + row] = l_i[r];
    }
  }
#pragma unroll
  for (int tv = 0; tv < 4; ++tv)
#pragma unroll
    for (int r = 0; r < 4; ++r) {
      int row = w * 16 + q * 4 + r;
      int col = tv * 16 + c;
      po[row * 64 + col] = (f16)oacc[tv][r];
    }
}

// ---------------- merge partials -> oh [2048][1024] f16 ----------------
__global__ __launch_bounds__(256) void k_merge(const f16* __restrict__ pO, const float* __restrict__ pML,
                                               f16* __restrict__ oh) {
  int head = blockIdx.x >> 4, I = blockIdx.x & 15;
  int S_ = ns2(I >> 1);
  int tid = threadIdx.x;
  int row = tid >> 1, half = tid & 1;
  int base = head * SLOTS_PER_HEAD + slot_base(I);
  float m[MAXS], lv[MAXS];
  float mstar = -INFINITY;
#pragma unroll
  for (int s = 0; s < MAXS; ++s)
    if (s < S_) {
      m[s] = pML[(size_t)(base + s) * 256 + row];
      lv[s] = pML[(size_t)(base + s) * 256 + 128 + row];
      mstar = fmaxf(mstar, m[s]);
    }
  float wt[MAXS];
  float lsum = 0.f;
#pragma unroll
  for (int s = 0; s < MAXS; ++s)
    if (s < S_) {
      wt[s] = __expf(m[s] - mstar);   // empty partials (m=-inf) get weight 0
      lsum += lv[s] * wt[s];
    }
  float rinv = __builtin_amdgcn_rcpf(lsum);
#pragma unroll
  for (int cc = 0; cc < 32; cc += 8) {
    float acc[8] = {0.f, 0.f, 0.f, 0.f, 0.f, 0.f, 0.f, 0.f};
#pragma unroll
    for (int s = 0; s < MAXS; ++s)
      if (s < S_) {
        f16x8 v = *(const f16x8*)(pO + (size_t)(base + s) * 8192 + row * 64 + half * 32 + cc);
#pragma unroll
        for (int e = 0; e < 8; ++e) acc[e] += wt[s] * (float)v[e];
      }
    f16x8 o;
#pragma unroll
    for (int e = 0; e < 8; ++e) o[e] = (f16)(acc[e] * rinv);
    *(f16x8*)(oh + (size_t)(I * 128 + row) * DIM + head * 64 + half * 32 + cc) = o;
  }
}

// ---------------- final GEMM: oh[2048,1024] @ WoT^T -> fp32, 128x128 tiles ----------------
__global__ __launch_bounds__(256) void k_gemm_out(const f16* __restrict__ A, const f16* __restrict__ B,
                                                  float* __restrict__ out) {
  __shared__ f16 sa[128 * 72];
  __shared__ f16 sb[128 * 72];
  int bx = blockIdx.x, by = blockIdx.y;
  int tid = threadIdx.x, w = tid >> 6, l = tid & 63, q = l >> 4, c = l & 15;
  f32x4 acc[2][8];
  const f32x4 zf = {0.f, 0.f, 0.f, 0.f};
  for (int i = 0; i < 2; ++i) for (int j = 0; j < 8; ++j) acc[i][j] = zf;
  for (int kt = 0; kt < DIM / 64; ++kt) {
    __syncthreads();
#pragma unroll
    for (int it = 0; it < 4; ++it) {
      int idx = it * 256 + tid; int r = idx >> 3, ch = idx & 7;
      *(float4*)(sa + r * 72 + ch * 8) = *(const float4*)(A + (size_t)(by * 128 + r) * DIM + kt * 64 + ch * 8);
      *(float4*)(sb + r * 72 + ch * 8) = *(const float4*)(B + (size_t)(bx * 128 + r) * DIM + kt * 64 + ch * 8);
    }
    __syncthreads();
#pragma unroll
    for (int ks = 0; ks < 2; ++ks) {
      f16x8 af[2], bf[8];
#pragma unroll
      for (int tr = 0; tr < 2; ++tr) af[tr] = *(const f16x8*)(sa + (w * 32 + tr * 16 + c) * 72 + ks * 32 + q * 8);
#pragma unroll
      for (int tc = 0; tc < 8; ++tc) bf[tc] = *(const f16x8*)(sb + (tc * 16 + c) * 72 + ks * 32 + q * 8);
#pragma unroll
      for (int tr = 0; tr < 2; ++tr)
#pragma unroll
        for (int tc = 0; tc < 8; ++tc)
          acc[tr][tc] = __builtin_amdgcn_mfma_f32_16x16x32_f16(af[tr], bf[tc], acc[tr][tc], 0, 0, 0);
    }
  }
#pragma unroll
  for (int tr = 0; tr < 2; ++tr)
#pragma unroll
    for (int tc = 0; tc < 8; ++tc)
#pragma unroll
      for (int r = 0; r < 4; ++r) {
        int row = by * 128 + w * 32 + tr * 16 + q * 4 + r;
        int col = bx * 128 + tc * 16 + c;
        out[(size_t)row * DIM + col] = acc[tr][tc][r];
      }
}

extern "C" void kernel_launch(void* const* d_in, const int* in_sizes, int n_in,
                              void* d_out, int out_size, void* d_ws, size_t ws_size,
                              hipStream_t stream) {
  const float* x  = (const float*)d_in[0];
  const float* Wq = (const float*)d_in[1];
  const float* Wo = (const float*)d_in[2];
  float* out = (float*)d_out;

  f16* ws = (f16*)d_ws;
  size_t off = 0;
  f16* q6   = ws + off; off += (size_t)6 * NHSD;                        // 25.2 MB
  f16* vuF  = ws + off; off += (size_t)NHSD;                            // 4.2 MB (vu^T frag tiles)
  f16* xhT  = ws + off; off += (size_t)SEQ * DIM;                       // 4.2 MB
  f16* WqTf = ws + off; off += (size_t)NCOLS * DIM;                     // 12.6 MB
  f16* WoT  = ws + off; off += (size_t)DIM * DIM;                       // 2.1 MB
  f16* oh   = ws + off; off += (size_t)SEQ * DIM;                       // 4.2 MB
  f16* pO   = ws + off; off += (size_t)NH * SLOTS_PER_HEAD * 128 * 64;  // 10.5 MB
  f16* lkT  = ws + off; off += (size_t)NH * NTILE * 128 * 128;          // 71.3 MB
  f16* t1dT = ws + off; off += (size_t)NH * 16 * 128 * 128;             // 8.4 MB (diag t1 only)
  f16* PPT  = ws + off; off += (size_t)NH * NTILE * 128 * 64;           // 35.7 MB (prefix tiles)
  float* pML = (float*)(ws + off); off += (size_t)NH * SLOTS_PER_HEAD * 256 * 2; // 0.66 MB
  // total ~180 MB of workspace

  k_prepA<<<dim3(16, 16), 256, 0, stream>>>(x, xhT);
  k_prepB<<<dim3(16, 48), 256, 0, stream>>>(Wq, WqTf);
  k_tcast<<<dim3(DIM / 64, DIM / 64), 256, 0, stream>>>(Wo, WoT, DIM, DIM);
  k_gemm_qkv<<<dim3(NCOLS / 128, SEQ / 128), 256, 0, stream>>>(xhT, WqTf, q6, vuF);
  k_t1lk<<<NH * 152, 256, 0, stream>>>(q6, t1dT, lkT);
  k_prefix<<<NH * 16, 256, 0, stream>>>(lkT, vuF, PPT);
  k_flash<<<NH * 40, 512, 0, stream>>>(q6, t1dT, lkT, PPT, pO, pML);
  k_merge<<<NH * 16, 256, 0, stream>>>(pO, pML, oh);
  k_gemm_out<<<dim3(DIM / 128, SEQ / 128), 256, 0, stream>>>(oh, WoT, out);
}